// Round 2
// baseline (380.532 us; speedup 1.0000x reference)
//
#include <hip/hip_runtime.h>
#include <hip/hip_bf16.h>

// ---------------------------------------------------------------------------
// AttentionHead: B=4, S=2048, D_IN=1024, D_OUT=1024
// Precision plan: Q,K path uses 2-term bf16 split (hi+lo) with 3-term MFMA
// (AH*BH + AH*BL + AL*BH) == ~fp32 accuracy on matrix cores. V/P path plain bf16.
//
// ws layout (byte offsets, MiB), high-water 186 MiB:
//   XH     @0    (48)  [3][8192][1024] bf16   hi(X) for k,v,q
//   XL     @48   (32)  [2][8192][1024] bf16   lo(X) for k,q
//   WTH    @80   (6)   [3][1024][1024] bf16   hi(W^T) K,V,Q
//   WTL    @86   (4)   [2][1024][1024] bf16   lo(W^T) K,Q
//   KH     @90   (16)  KL @106 (16)  QH @122 (16)  QL @138 (16)
//   V      @154  (16)  VT @170 (16)               -> end 186
//   SCORES @0    (64)  f32 (alias XH+XLk; dead after projections)
//   P      @64   (32)  bf16 (alias XLq+WT+KH-head; dead after scores GEMM)
// ---------------------------------------------------------------------------

typedef __attribute__((ext_vector_type(4))) float  f32x4;
typedef __attribute__((ext_vector_type(8))) __bf16 bf16x8;
typedef __attribute__((ext_vector_type(4))) __bf16 bf16x4;

constexpr size_t MiB = 1u << 20;
constexpr size_t MK  = (size_t)8192 * 1024;   // elements per [8192][1024]
constexpr size_t WS  = (size_t)1024 * 1024;   // elements per [1024][1024]

__device__ __forceinline__ void gload_lds16(const void* g, void* l) {
  __builtin_amdgcn_global_load_lds(
      (const __attribute__((address_space(1))) unsigned int*)g,
      (__attribute__((address_space(3))) unsigned int*)l, 16, 0, 0);
}

// ---------------------------------------------------------------------------
// X fp32 -> XH (all 3) and XL (k,q only), 4 elems/thread.
__global__ __launch_bounds__(256) void split_x(
    const float* __restrict__ x0, const float* __restrict__ x1,
    const float* __restrict__ x2, __bf16* __restrict__ XH,
    __bf16* __restrict__ XL)
{
  const int z = blockIdx.z;
  const float* x = z == 0 ? x0 : (z == 1 ? x1 : x2);
  size_t i = ((size_t)blockIdx.x * 256 + threadIdx.x) * 4;
  float4 v = *(const float4*)(x + i);
  bf16x4 h = {(__bf16)v.x, (__bf16)v.y, (__bf16)v.z, (__bf16)v.w};
  *(bf16x4*)(XH + (size_t)z * MK + i) = h;
  if (z != 1) {
    bf16x4 l = {(__bf16)(v.x - (float)h[0]), (__bf16)(v.y - (float)h[1]),
                (__bf16)(v.z - (float)h[2]), (__bf16)(v.w - (float)h[3])};
    *(bf16x4*)(XL + (size_t)(z == 0 ? 0 : 1) * MK + i) = l;
  }
}

// ---------------------------------------------------------------------------
// W [1024][1024] f32 -> WTH (all 3), WTL (K,Q) transposed bf16.
__global__ __launch_bounds__(256) void transpose_split_w(
    const float* __restrict__ w0, const float* __restrict__ w1,
    const float* __restrict__ w2, __bf16* __restrict__ WTH,
    __bf16* __restrict__ WTL)
{
  const int z = blockIdx.z;
  const float* W = z == 0 ? w0 : (z == 1 ? w1 : w2);
  __bf16* oh = WTH + (size_t)z * WS;
  __bf16* ol = WTL + (size_t)(z == 0 ? 0 : 1) * WS;  // valid only z!=1
  __shared__ float tile[32][33];
  const int bx = blockIdx.x * 32;   // n
  const int by = blockIdx.y * 32;   // k
  const int tx = threadIdx.x & 31, ty = threadIdx.x >> 5;
  #pragma unroll
  for (int r = 0; r < 32; r += 8)
    tile[ty + r][tx] = W[(size_t)(by + ty + r) * 1024 + bx + tx];
  __syncthreads();
  #pragma unroll
  for (int r = 0; r < 32; r += 8) {
    float w = tile[tx][ty + r];
    __bf16 h = (__bf16)w;
    oh[(size_t)(bx + ty + r) * 1024 + by + tx] = h;
    if (z != 1)
      ol[(size_t)(bx + ty + r) * 1024 + by + tx] = (__bf16)(w - (float)h);
  }
}

// ---------------------------------------------------------------------------
// V [z][2048][1024] bf16 -> Vt [z][1024][2048] bf16
__global__ __launch_bounds__(256) void transpose_v(
    const __bf16* __restrict__ V, __bf16* __restrict__ Vt)
{
  const __bf16* v = V + (size_t)blockIdx.z * 2048 * 1024;
  __bf16* o = Vt + (size_t)blockIdx.z * 1024 * 2048;
  __shared__ __bf16 tile[32][33];
  const int bx = blockIdx.x * 32;   // e
  const int by = blockIdx.y * 32;   // s
  const int tx = threadIdx.x & 31, ty = threadIdx.x >> 5;
  #pragma unroll
  for (int r = 0; r < 32; r += 8)
    tile[ty + r][tx] = v[(size_t)(by + ty + r) * 1024 + bx + tx];
  __syncthreads();
  #pragma unroll
  for (int r = 0; r < 32; r += 8)
    o[(size_t)(bx + ty + r) * 2048 + by + tx] = tile[tx][ty + r];
}

// ---------------------------------------------------------------------------
// Plain bt GEMM: C[m][n] = scale * sum_k A[m][k]*Bt[n][k]. 128x128, BK=32.
template <typename OutT>
__global__ __launch_bounds__(256, 2) void gemm_bt(
    const __bf16* __restrict__ A, size_t sAz,
    const __bf16* __restrict__ Bt, size_t sBz,
    OutT* __restrict__ C, size_t sCz,
    int M, int N, int K, float scale)
{
  A  += (size_t)blockIdx.z * sAz;
  Bt += (size_t)blockIdx.z * sBz;
  C  += (size_t)blockIdx.z * sCz;
  const int m0 = blockIdx.y * 128;
  const int n0 = blockIdx.x * 128;

  __shared__ __bf16 ldsA[128 * 32];
  __shared__ __bf16 ldsB[128 * 32];

  const int t = threadIdx.x;
  const int srow = t >> 2;
  const int scol = (t & 3) * 8;
  const __bf16* aBase = A  + (size_t)(m0 + srow) * K + scol;
  const __bf16* bBase = Bt + (size_t)(n0 + srow) * K + scol;
  const size_t rowStride64 = (size_t)64 * K;
  __bf16* ldsA_dst = ldsA + t * 8;
  __bf16* ldsB_dst = ldsB + t * 8;

  const int lane = t & 63;
  const int wave = t >> 6;
  const int wm = (wave >> 1) * 64;
  const int wn = (wave & 1) * 64;
  const int fr = lane & 15;
  const int fq = lane >> 4;
  const __bf16* ra = ldsA + (wm + fr) * 32 + fq * 8;
  const __bf16* rb = ldsB + (wn + fr) * 32 + fq * 8;

  f32x4 acc[4][4] = {};

  for (int kt = 0; kt < K; kt += 32) {
    __syncthreads();
    gload_lds16(aBase + kt,               ldsA_dst);
    gload_lds16(aBase + kt + rowStride64, ldsA_dst + 64 * 32);
    gload_lds16(bBase + kt,               ldsB_dst);
    gload_lds16(bBase + kt + rowStride64, ldsB_dst + 64 * 32);
    __syncthreads();

    bf16x8 af[4], bfr[4];
    #pragma unroll
    for (int i = 0; i < 4; ++i) af[i]  = *(const bf16x8*)(ra + i * 16 * 32);
    #pragma unroll
    for (int j = 0; j < 4; ++j) bfr[j] = *(const bf16x8*)(rb + j * 16 * 32);
    #pragma unroll
    for (int i = 0; i < 4; ++i)
      #pragma unroll
      for (int j = 0; j < 4; ++j)
        acc[i][j] = __builtin_amdgcn_mfma_f32_16x16x32_bf16(
            af[i], bfr[j], acc[i][j], 0, 0, 0);
  }

  const int er = fq * 4;
  #pragma unroll
  for (int i = 0; i < 4; ++i)
    #pragma unroll
    for (int j = 0; j < 4; ++j) {
      size_t base = (size_t)(m0 + wm + i * 16 + er) * N + (n0 + wn + j * 16 + fr);
      #pragma unroll
      for (int r = 0; r < 4; ++r)
        C[base + (size_t)r * N] = (OutT)(acc[i][j][r] * scale);
    }
}

// ---------------------------------------------------------------------------
// Split-3 bt GEMM: C = AH*BH^T + AH*BL^T + AL*BH^T  (~fp32 accurate).
// SPLIT_OUT: write CH=bf16(c), CL=bf16(c-CH) to C0,C1. Else: fp32*scale to C0.
template <bool SPLIT_OUT>
__global__ __launch_bounds__(256, 2) void gemm_bt_s3(
    const __bf16* __restrict__ AH, const __bf16* __restrict__ AL,
    size_t sAHz, size_t sALz,
    const __bf16* __restrict__ BH, const __bf16* __restrict__ BL,
    size_t sBHz, size_t sBLz,
    void* __restrict__ C0v, void* __restrict__ C1v, size_t sCz,
    int M, int N, int K, float scale)
{
  AH += (size_t)blockIdx.z * sAHz;
  AL += (size_t)blockIdx.z * sALz;
  BH += (size_t)blockIdx.z * sBHz;
  BL += (size_t)blockIdx.z * sBLz;
  const int m0 = blockIdx.y * 128;
  const int n0 = blockIdx.x * 128;

  __shared__ __bf16 lAH[128 * 32];
  __shared__ __bf16 lAL[128 * 32];
  __shared__ __bf16 lBH[128 * 32];
  __shared__ __bf16 lBL[128 * 32];

  const int t = threadIdx.x;
  const int srow = t >> 2;
  const int scol = (t & 3) * 8;
  const size_t aOff = (size_t)(m0 + srow) * K + scol;
  const size_t bOff = (size_t)(n0 + srow) * K + scol;
  const size_t rs64 = (size_t)64 * K;
  const int ldst = t * 8;

  const int lane = t & 63;
  const int wave = t >> 6;
  const int wm = (wave >> 1) * 64;
  const int wn = (wave & 1) * 64;
  const int fr = lane & 15;
  const int fq = lane >> 4;
  const int raOff = (wm + fr) * 32 + fq * 8;
  const int rbOff = (wn + fr) * 32 + fq * 8;

  f32x4 acc[4][4] = {};

  for (int kt = 0; kt < K; kt += 32) {
    __syncthreads();
    gload_lds16(AH + aOff + kt,        lAH + ldst);
    gload_lds16(AH + aOff + kt + rs64, lAH + ldst + 64 * 32);
    gload_lds16(AL + aOff + kt,        lAL + ldst);
    gload_lds16(AL + aOff + kt + rs64, lAL + ldst + 64 * 32);
    gload_lds16(BH + bOff + kt,        lBH + ldst);
    gload_lds16(BH + bOff + kt + rs64, lBH + ldst + 64 * 32);
    gload_lds16(BL + bOff + kt,        lBL + ldst);
    gload_lds16(BL + bOff + kt + rs64, lBL + ldst + 64 * 32);
    __syncthreads();

    bf16x8 ah[4], al[4], bh[4], bl[4];
    #pragma unroll
    for (int i = 0; i < 4; ++i) {
      ah[i] = *(const bf16x8*)(lAH + raOff + i * 16 * 32);
      al[i] = *(const bf16x8*)(lAL + raOff + i * 16 * 32);
    }
    #pragma unroll
    for (int j = 0; j < 4; ++j) {
      bh[j] = *(const bf16x8*)(lBH + rbOff + j * 16 * 32);
      bl[j] = *(const bf16x8*)(lBL + rbOff + j * 16 * 32);
    }
    #pragma unroll
    for (int i = 0; i < 4; ++i)
      #pragma unroll
      for (int j = 0; j < 4; ++j) {
        acc[i][j] = __builtin_amdgcn_mfma_f32_16x16x32_bf16(ah[i], bh[j], acc[i][j], 0, 0, 0);
        acc[i][j] = __builtin_amdgcn_mfma_f32_16x16x32_bf16(ah[i], bl[j], acc[i][j], 0, 0, 0);
        acc[i][j] = __builtin_amdgcn_mfma_f32_16x16x32_bf16(al[i], bh[j], acc[i][j], 0, 0, 0);
      }
  }

  const int er = fq * 4;
  #pragma unroll
  for (int i = 0; i < 4; ++i)
    #pragma unroll
    for (int j = 0; j < 4; ++j) {
      size_t base = (size_t)(m0 + wm + i * 16 + er) * N + (n0 + wn + j * 16 + fr);
      #pragma unroll
      for (int r = 0; r < 4; ++r) {
        float v = acc[i][j][r];
        size_t idx = base + (size_t)r * N;
        if (SPLIT_OUT) {
          __bf16* CH = (__bf16*)C0v + (size_t)blockIdx.z * sCz;
          __bf16* CL = (__bf16*)C1v + (size_t)blockIdx.z * sCz;
          __bf16 h = (__bf16)v;
          CH[idx] = h;
          CL[idx] = (__bf16)(v - (float)h);
        } else {
          float* C = (float*)C0v + (size_t)blockIdx.z * sCz;
          C[idx] = v * scale;
        }
      }
    }
}

// ---------------------------------------------------------------------------
// Row softmax: scores [8192 rows][2048] f32 -> P bf16.
__global__ __launch_bounds__(256) void softmax_rows(
    const float* __restrict__ S, __bf16* __restrict__ P)
{
  const size_t row = blockIdx.x;
  const float4* srow = (const float4*)(S + row * 2048);
  const int t = threadIdx.x;
  float4 v0 = srow[t];
  float4 v1 = srow[t + 256];

  float m = fmaxf(fmaxf(fmaxf(v0.x, v0.y), fmaxf(v0.z, v0.w)),
                  fmaxf(fmaxf(v1.x, v1.y), fmaxf(v1.z, v1.w)));
  #pragma unroll
  for (int o = 32; o >= 1; o >>= 1) m = fmaxf(m, __shfl_xor(m, o));
  __shared__ float redm[4];
  if ((t & 63) == 0) redm[t >> 6] = m;
  __syncthreads();
  m = fmaxf(fmaxf(redm[0], redm[1]), fmaxf(redm[2], redm[3]));

  float e[8];
  e[0] = __expf(v0.x - m); e[1] = __expf(v0.y - m);
  e[2] = __expf(v0.z - m); e[3] = __expf(v0.w - m);
  e[4] = __expf(v1.x - m); e[5] = __expf(v1.y - m);
  e[6] = __expf(v1.z - m); e[7] = __expf(v1.w - m);
  float s = e[0] + e[1] + e[2] + e[3] + e[4] + e[5] + e[6] + e[7];
  #pragma unroll
  for (int o = 32; o >= 1; o >>= 1) s += __shfl_xor(s, o);
  __shared__ float reds[4];
  if ((t & 63) == 0) reds[t >> 6] = s;
  __syncthreads();
  s = reds[0] + reds[1] + reds[2] + reds[3];

  const float inv = 1.0f / s;
  bf16x4 p0 = {(__bf16)(e[0] * inv), (__bf16)(e[1] * inv),
               (__bf16)(e[2] * inv), (__bf16)(e[3] * inv)};
  bf16x4 p1 = {(__bf16)(e[4] * inv), (__bf16)(e[5] * inv),
               (__bf16)(e[6] * inv), (__bf16)(e[7] * inv)};
  bf16x4* prow = (bf16x4*)(P + row * 2048);
  prow[t] = p0;
  prow[t + 256] = p1;
}

// ---------------------------------------------------------------------------
extern "C" void kernel_launch(void* const* d_in, const int* in_sizes, int n_in,
                              void* d_out, int out_size, void* d_ws, size_t ws_size,
                              hipStream_t stream)
{
  const float* Xk = (const float*)d_in[0];
  const float* Xv = (const float*)d_in[1];
  const float* Xq = (const float*)d_in[2];
  const float* WK = (const float*)d_in[3];
  const float* WV = (const float*)d_in[4];
  const float* WQ = (const float*)d_in[5];
  float* out = (float*)d_out;
  char* ws = (char*)d_ws;

  __bf16* XH  = (__bf16*)(ws);               // 0..48 MiB
  __bf16* XL  = (__bf16*)(ws + 48 * MiB);    // 48..80 (k,q)
  __bf16* WTH = (__bf16*)(ws + 80 * MiB);    // 80..86
  __bf16* WTL = (__bf16*)(ws + 86 * MiB);    // 86..90 (K,Q)
  __bf16* KH  = (__bf16*)(ws + 90 * MiB);
  __bf16* KL  = (__bf16*)(ws + 106 * MiB);
  __bf16* QH  = (__bf16*)(ws + 122 * MiB);
  __bf16* QL  = (__bf16*)(ws + 138 * MiB);
  __bf16* V   = (__bf16*)(ws + 154 * MiB);
  __bf16* VT  = (__bf16*)(ws + 170 * MiB);   // ..186
  float*  SCORES = (float*)(ws);             // alias XH+XLk (dead post-proj)
  __bf16* P   = (__bf16*)(ws + 64 * MiB);    // alias XLq+WT+KH-head (dead post-scores)

  // 1) split X -> hi (k,v,q) + lo (k,q)
  split_x<<<dim3(8192, 1, 3), 256, 0, stream>>>(Xk, Xv, Xq, XH, XL);
  // 2) W -> W^T hi (K,V,Q) + lo (K,Q)
  transpose_split_w<<<dim3(32, 32, 3), 256, 0, stream>>>(WK, WV, WQ, WTH, WTL);
  // 3) V projection (plain bf16): V = XH[v] @ WTH[V]^T
  gemm_bt<__bf16><<<dim3(8, 64, 1), 256, 0, stream>>>(
      XH + MK, 0, WTH + WS, 0, V, 0, 8192, 1024, 1024, 1.0f);
  // 4) K,Q projections (split3, split output): z=0 -> K, z=1 -> Q
  gemm_bt_s3<true><<<dim3(8, 64, 2), 256, 0, stream>>>(
      XH, XL, 2 * MK, MK,          // AH: XH[k]@0, XH[q]@2MK ; AL: XL[k]@0, XL[q]@MK
      WTH, WTL, 2 * WS, WS,        // BH: WTH[K]@0, WTH[Q]@2WS ; BL
      KH, KL, 2 * MK,              // CH: KH@0, QH@+2MK(=32MiB) ; CL: KL, QL
      8192, 1024, 1024, 1.0f);
  // 5) V^T per batch
  transpose_v<<<dim3(32, 64, 4), 256, 0, stream>>>(V, VT);
  // 6) scores (split3, fp32 out): scores[b] = Q[b]@K[b]^T / sqrt(2048)
  gemm_bt_s3<false><<<dim3(16, 16, 4), 256, 0, stream>>>(
      QH, QL, (size_t)2048 * 1024, (size_t)2048 * 1024,
      KH, KL, (size_t)2048 * 1024, (size_t)2048 * 1024,
      SCORES, nullptr, (size_t)2048 * 2048,
      2048, 2048, 1024, 0.022097086912079608f);
  // 7) softmax -> P bf16
  softmax_rows<<<dim3(8192), 256, 0, stream>>>(SCORES, P);
  // 8) out[b] = P[b] @ VT[b]^T
  gemm_bt<float><<<dim3(8, 16, 4), 256, 0, stream>>>(
      P, (size_t)2048 * 2048, VT, (size_t)1024 * 2048,
      out, (size_t)2048 * 1024,
      2048, 1024, 2048, 1.0f);
}

// Round 3
// 347.820 us; speedup vs baseline: 1.0940x; 1.0940x over previous
//
#include <hip/hip_runtime.h>
#include <hip/hip_bf16.h>

// ---------------------------------------------------------------------------
// AttentionHead B=4,S=2048,D=1024. Split-bf16 (hi+lo, 3-term) Q/K path.
// GEMM: 256xBN tile, BK=32, 4-deep LDS pipeline (counted vmcnt, T2 swizzle,
// T5 setprio). ws layout identical to round-2 (high-water 186 MiB).
// ---------------------------------------------------------------------------

typedef __attribute__((ext_vector_type(4))) float  f32x4;
typedef __attribute__((ext_vector_type(8))) __bf16 bf16x8;
typedef __attribute__((ext_vector_type(4))) __bf16 bf16x4;

constexpr size_t MiB = 1u << 20;
constexpr size_t MK  = (size_t)8192 * 1024;
constexpr size_t WSZ = (size_t)1024 * 1024;

__device__ __forceinline__ void gload_lds16(const void* g, void* l) {
  __builtin_amdgcn_global_load_lds(
      (const __attribute__((address_space(1))) unsigned int*)g,
      (__attribute__((address_space(3))) unsigned int*)l, 16, 0, 0);
}

#define MFMA16(a, b, c) __builtin_amdgcn_mfma_f32_16x16x32_bf16(a, b, c, 0, 0, 0)

// ---------------------------------------------------------------------------
__global__ __launch_bounds__(256) void split_x(
    const float* __restrict__ x0, const float* __restrict__ x1,
    const float* __restrict__ x2, __bf16* __restrict__ XH,
    __bf16* __restrict__ XL)
{
  const int z = blockIdx.z;
  const float* x = z == 0 ? x0 : (z == 1 ? x1 : x2);
  size_t i = ((size_t)blockIdx.x * 256 + threadIdx.x) * 4;
  float4 v = *(const float4*)(x + i);
  bf16x4 h = {(__bf16)v.x, (__bf16)v.y, (__bf16)v.z, (__bf16)v.w};
  *(bf16x4*)(XH + (size_t)z * MK + i) = h;
  if (z != 1) {
    bf16x4 l = {(__bf16)(v.x - (float)h[0]), (__bf16)(v.y - (float)h[1]),
                (__bf16)(v.z - (float)h[2]), (__bf16)(v.w - (float)h[3])};
    *(bf16x4*)(XL + (size_t)(z == 0 ? 0 : 1) * MK + i) = l;
  }
}

// ---------------------------------------------------------------------------
__global__ __launch_bounds__(256) void transpose_split_w(
    const float* __restrict__ w0, const float* __restrict__ w1,
    const float* __restrict__ w2, __bf16* __restrict__ WTH,
    __bf16* __restrict__ WTL)
{
  const int z = blockIdx.z;
  const float* W = z == 0 ? w0 : (z == 1 ? w1 : w2);
  __bf16* oh = WTH + (size_t)z * WSZ;
  __bf16* ol = WTL + (size_t)(z == 0 ? 0 : 1) * WSZ;
  __shared__ float tile[32][33];
  const int bx = blockIdx.x * 32;
  const int by = blockIdx.y * 32;
  const int tx = threadIdx.x & 31, ty = threadIdx.x >> 5;
  #pragma unroll
  for (int r = 0; r < 32; r += 8)
    tile[ty + r][tx] = W[(size_t)(by + ty + r) * 1024 + bx + tx];
  __syncthreads();
  #pragma unroll
  for (int r = 0; r < 32; r += 8) {
    float w = tile[tx][ty + r];
    __bf16 h = (__bf16)w;
    oh[(size_t)(bx + ty + r) * 1024 + by + tx] = h;
    if (z != 1)
      ol[(size_t)(bx + ty + r) * 1024 + by + tx] = (__bf16)(w - (float)h);
  }
}

// ---------------------------------------------------------------------------
__global__ __launch_bounds__(256) void transpose_v(
    const __bf16* __restrict__ V, __bf16* __restrict__ Vt)
{
  const __bf16* v = V + (size_t)blockIdx.z * 2048 * 1024;
  __bf16* o = Vt + (size_t)blockIdx.z * 1024 * 2048;
  __shared__ __bf16 tile[32][33];
  const int bx = blockIdx.x * 32;
  const int by = blockIdx.y * 32;
  const int tx = threadIdx.x & 31, ty = threadIdx.x >> 5;
  #pragma unroll
  for (int r = 0; r < 32; r += 8)
    tile[ty + r][tx] = v[(size_t)(by + ty + r) * 1024 + bx + tx];
  __syncthreads();
  #pragma unroll
  for (int r = 0; r < 32; r += 8)
    o[(size_t)(bx + ty + r) * 2048 + by + tx] = tile[tx][ty + r];
}

// ---------------------------------------------------------------------------
// gemm256: C[m][n] = scale * sum_terms sum_k A_t[m][k] * B_t[n][k]
// Tile 256 x BN, BK=32, 512 threads (8 waves). 4-deep LDS pipeline:
// buffers t%4; stage tile t+3 during tile t; boundary s_waitcnt vmcnt(2*LPT).
// T2 swizzle: phys_colbyte = logical ^ (((row>>1)&3)<<4); applied on the
// pre-swizzled GLOBAL source (linear LDS dest, rule 21) and on ds_reads.
// MODE 0: f32*scale -> C0 ; 1: bf16 -> C0 ; 2: hi/lo bf16 split -> C0,C1.
template <int MODE, int BN>
__global__ __launch_bounds__(512, 2) void gemm256(
    const __bf16* __restrict__ A0t, const __bf16* __restrict__ A1t,
    const __bf16* __restrict__ A2t, size_t sA0, size_t sA1, size_t sA2,
    const __bf16* __restrict__ B0t, const __bf16* __restrict__ B1t,
    const __bf16* __restrict__ B2t, size_t sB0, size_t sB1, size_t sB2,
    void* __restrict__ C0v, void* __restrict__ C1v, size_t sCz,
    int N, int K, int nterms, float scale)
{
  extern __shared__ char lds[];
  constexpr int MR  = (BN == 256) ? 8 : 4;   // 16-row m-tiles per wave
  constexpr int BB  = BN * 64;               // B tile bytes ([BN][32] bf16)
  char* ldsAb = lds;                         // 4 x 16384
  char* ldsBb = lds + 65536;                 // 4 x BB

  const int z = blockIdx.z;
  const __bf16* A0 = A0t + (size_t)z * sA0;
  const __bf16* A1 = A1t + (size_t)z * sA1;
  const __bf16* A2 = A2t + (size_t)z * sA2;
  const __bf16* B0 = B0t + (size_t)z * sB0;
  const __bf16* B1 = B1t + (size_t)z * sB1;
  const __bf16* B2 = B2t + (size_t)z * sB2;

  const int gm0 = blockIdx.y * 256;
  const int gn0 = blockIdx.x * BN;
  const int tid = threadIdx.x;
  const int lane = tid & 63, wave = tid >> 6;
  const int wm = (BN == 256) ? (wave >> 2) * 128 : (wave >> 1) * 64;
  const int wn = (BN == 256) ? (wave & 3) * 64 : (wave & 1) * 64;
  const int fr = lane & 15, fq = lane >> 4;

  const int KT  = K >> 5;          // K-tiles per term
  const int nkt = nterms * KT;

  // staging: thread t, load l -> LDS linear byte (l*8192 + tid*16);
  // row = l*128 + tid>>2, src colbyte = ((tid&3)*16) ^ (((row>>1)&3)<<4)
  const int cbs = (((tid & 3) ^ ((tid >> 3) & 3)) << 4);
  const size_t sAoff = (size_t)(gm0 + (tid >> 2)) * K + (cbs >> 1);
  const size_t sBoff = (size_t)(gn0 + (tid >> 2)) * K + (cbs >> 1);
  // fragment reads (swizzled): row stride 64B
  const int cbr  = (fq * 16) ^ (((fr >> 1) & 3) << 4);
  const int arow = (wm + fr) * 64 + cbr;   // + m*1024
  const int brow = (wn + fr) * 64 + cbr;   // + n*1024

  f32x4 acc[MR][4] = {};

  // prologue: stage tiles 0,1,2
  for (int tp = 0; tp < 3; ++tp) {
    const int term = tp / KT;
    const int kk = (tp - term * KT) << 5;
    const __bf16* As = term == 0 ? A0 : (term == 1 ? A1 : A2);
    const __bf16* Bs = term == 0 ? B0 : (term == 1 ? B1 : B2);
    const __bf16* gA = As + sAoff + kk;
    const __bf16* gB = Bs + sBoff + kk;
    char* dA = ldsAb + tp * 16384 + tid * 16;
    char* dB = ldsBb + tp * BB + tid * 16;
    gload_lds16(gA, dA);
    gload_lds16(gA + (size_t)128 * K, dA + 8192);
    gload_lds16(gB, dB);
    if constexpr (BN == 256) gload_lds16(gB + (size_t)128 * K, dB + 8192);
  }
  if constexpr (BN == 256) asm volatile("s_waitcnt vmcnt(8)" ::: "memory");
  else                     asm volatile("s_waitcnt vmcnt(6)" ::: "memory");
  __builtin_amdgcn_s_barrier();
  __builtin_amdgcn_sched_barrier(0);

  for (int t = 0; t < nkt; ++t) {
    const char* pA = ldsAb + (t & 3) * 16384;
    const char* pB = ldsBb + (t & 3) * BB;
    const int tp = t + 3;
    const bool st = tp < nkt;
    const int tpc = st ? tp : 0;
    const int term = tpc / KT;
    const int kk = (tpc - term * KT) << 5;
    const __bf16* As = term == 0 ? A0 : (term == 1 ? A1 : A2);
    const __bf16* Bs = term == 0 ? B0 : (term == 1 ? B1 : B2);
    const __bf16* gA = As + sAoff + kk;
    const __bf16* gB = Bs + sBoff + kk;
    char* dA = ldsAb + (tp & 3) * 16384 + tid * 16;
    char* dB = ldsBb + (tp & 3) * BB + tid * 16;

    // ---- phase 0: stage 2, read B + low A, 16/8 MFMA ----
    if (st) { gload_lds16(gA, dA); gload_lds16(gB, dB); }
    bf16x8 bfr[4], af[MR / 2];
    #pragma unroll
    for (int n = 0; n < 4; ++n)
      bfr[n] = *(const bf16x8*)(pB + brow + n * 1024);
    #pragma unroll
    for (int m = 0; m < MR / 2; ++m)
      af[m] = *(const bf16x8*)(pA + arow + m * 1024);
    __builtin_amdgcn_s_setprio(1);
    #pragma unroll
    for (int m = 0; m < MR / 2; ++m)
      #pragma unroll
      for (int n = 0; n < 4; ++n)
        acc[m][n] = MFMA16(af[m], bfr[n], acc[m][n]);
    __builtin_amdgcn_s_setprio(0);
    __builtin_amdgcn_s_barrier();
    __builtin_amdgcn_sched_barrier(0);

    // ---- phase 1: stage rest, read high A, 16/8 MFMA ----
    if (st) {
      gload_lds16(gA + (size_t)128 * K, dA + 8192);
      if constexpr (BN == 256) gload_lds16(gB + (size_t)128 * K, dB + 8192);
    }
    #pragma unroll
    for (int m = 0; m < MR / 2; ++m)
      af[m] = *(const bf16x8*)(pA + arow + (m + MR / 2) * 1024);
    __builtin_amdgcn_s_setprio(1);
    #pragma unroll
    for (int m = 0; m < MR / 2; ++m)
      #pragma unroll
      for (int n = 0; n < 4; ++n)
        acc[m + MR / 2][n] = MFMA16(af[m], bfr[n], acc[m + MR / 2][n]);
    __builtin_amdgcn_s_setprio(0);
    // boundary: tile t+1 (staged 3 tiles ago) must have landed; allow the
    // newest 2 tiles (2*LPT loads) to stay in flight.
    if constexpr (BN == 256) asm volatile("s_waitcnt vmcnt(8)" ::: "memory");
    else                     asm volatile("s_waitcnt vmcnt(6)" ::: "memory");
    __builtin_amdgcn_s_barrier();
    __builtin_amdgcn_sched_barrier(0);
  }

  // epilogue: C/D layout col=fr, row=fq*4+r  [verified r2]
  const int erow = gm0 + wm + fq * 4;
  const int ecol = gn0 + wn + fr;
  if constexpr (MODE == 0) {
    float* C = (float*)C0v + (size_t)z * sCz;
    #pragma unroll
    for (int m = 0; m < MR; ++m)
      #pragma unroll
      for (int n = 0; n < 4; ++n) {
        size_t base = (size_t)(erow + m * 16) * N + (ecol + n * 16);
        #pragma unroll
        for (int r = 0; r < 4; ++r)
          C[base + (size_t)r * N] = acc[m][n][r] * scale;
      }
  } else if constexpr (MODE == 1) {
    __bf16* C = (__bf16*)C0v + (size_t)z * sCz;
    #pragma unroll
    for (int m = 0; m < MR; ++m)
      #pragma unroll
      for (int n = 0; n < 4; ++n) {
        size_t base = (size_t)(erow + m * 16) * N + (ecol + n * 16);
        #pragma unroll
        for (int r = 0; r < 4; ++r)
          C[base + (size_t)r * N] = (__bf16)acc[m][n][r];
      }
  } else {
    __bf16* CH = (__bf16*)C0v + (size_t)z * sCz;
    __bf16* CL = (__bf16*)C1v + (size_t)z * sCz;
    #pragma unroll
    for (int m = 0; m < MR; ++m)
      #pragma unroll
      for (int n = 0; n < 4; ++n) {
        size_t base = (size_t)(erow + m * 16) * N + (ecol + n * 16);
        #pragma unroll
        for (int r = 0; r < 4; ++r) {
          float v = acc[m][n][r];
          __bf16 h = (__bf16)v;
          CH[base + (size_t)r * N] = h;
          CL[base + (size_t)r * N] = (__bf16)(v - (float)h);
        }
      }
  }
}

// ---------------------------------------------------------------------------
__global__ __launch_bounds__(256) void softmax_rows(
    const float* __restrict__ S, __bf16* __restrict__ P)
{
  const size_t row = blockIdx.x;
  const float4* srow = (const float4*)(S + row * 2048);
  const int t = threadIdx.x;
  float4 v0 = srow[t];
  float4 v1 = srow[t + 256];

  float m = fmaxf(fmaxf(fmaxf(v0.x, v0.y), fmaxf(v0.z, v0.w)),
                  fmaxf(fmaxf(v1.x, v1.y), fmaxf(v1.z, v1.w)));
  #pragma unroll
  for (int o = 32; o >= 1; o >>= 1) m = fmaxf(m, __shfl_xor(m, o));
  __shared__ float redm[4];
  if ((t & 63) == 0) redm[t >> 6] = m;
  __syncthreads();
  m = fmaxf(fmaxf(redm[0], redm[1]), fmaxf(redm[2], redm[3]));

  float e[8];
  e[0] = __expf(v0.x - m); e[1] = __expf(v0.y - m);
  e[2] = __expf(v0.z - m); e[3] = __expf(v0.w - m);
  e[4] = __expf(v1.x - m); e[5] = __expf(v1.y - m);
  e[6] = __expf(v1.z - m); e[7] = __expf(v1.w - m);
  float s = e[0] + e[1] + e[2] + e[3] + e[4] + e[5] + e[6] + e[7];
  #pragma unroll
  for (int o = 32; o >= 1; o >>= 1) s += __shfl_xor(s, o);
  __shared__ float reds[4];
  if ((t & 63) == 0) reds[t >> 6] = s;
  __syncthreads();
  s = reds[0] + reds[1] + reds[2] + reds[3];

  const float inv = 1.0f / s;
  bf16x4 p0 = {(__bf16)(e[0] * inv), (__bf16)(e[1] * inv),
               (__bf16)(e[2] * inv), (__bf16)(e[3] * inv)};
  bf16x4 p1 = {(__bf16)(e[4] * inv), (__bf16)(e[5] * inv),
               (__bf16)(e[6] * inv), (__bf16)(e[7] * inv)};
  bf16x4* prow = (bf16x4*)(P + row * 2048);
  prow[t] = p0;
  prow[t + 256] = p1;
}

// ---------------------------------------------------------------------------
extern "C" void kernel_launch(void* const* d_in, const int* in_sizes, int n_in,
                              void* d_out, int out_size, void* d_ws, size_t ws_size,
                              hipStream_t stream)
{
  const float* Xk = (const float*)d_in[0];
  const float* Xv = (const float*)d_in[1];
  const float* Xq = (const float*)d_in[2];
  const float* WK = (const float*)d_in[3];
  const float* WV = (const float*)d_in[4];
  const float* WQ = (const float*)d_in[5];
  float* out = (float*)d_out;
  char* ws = (char*)d_ws;

  __bf16* XH  = (__bf16*)(ws);               // 0..48 MiB
  __bf16* XL  = (__bf16*)(ws + 48 * MiB);    // 48..80 (k,q)
  __bf16* WTH = (__bf16*)(ws + 80 * MiB);
  __bf16* WTL = (__bf16*)(ws + 86 * MiB);
  __bf16* KH  = (__bf16*)(ws + 90 * MiB);
  __bf16* KL  = (__bf16*)(ws + 106 * MiB);
  __bf16* QH  = (__bf16*)(ws + 122 * MiB);
  __bf16* QL  = (__bf16*)(ws + 138 * MiB);
  __bf16* V   = (__bf16*)(ws + 154 * MiB);
  __bf16* VT  = (__bf16*)(ws + 170 * MiB);   // ..186
  float*  SCORES = (float*)(ws);             // alias XH+XLk (dead post-proj)
  __bf16* P   = (__bf16*)(ws + 64 * MiB);    // alias (dead post-scores)

  const size_t S21 = (size_t)2048 * 1024;

  // allow >64 KiB dynamic LDS (defensive; ignore rc)
  auto* fKQ = gemm256<2, 256>;
  auto* fSC = gemm256<0, 256>;
  auto* fV  = gemm256<1, 128>;
  auto* fPV = gemm256<0, 128>;
  (void)hipFuncSetAttribute((const void*)fKQ, hipFuncAttributeMaxDynamicSharedMemorySize, 131072);
  (void)hipFuncSetAttribute((const void*)fSC, hipFuncAttributeMaxDynamicSharedMemorySize, 131072);
  (void)hipFuncSetAttribute((const void*)fV,  hipFuncAttributeMaxDynamicSharedMemorySize, 98304);
  (void)hipFuncSetAttribute((const void*)fPV, hipFuncAttributeMaxDynamicSharedMemorySize, 98304);

  // 1) split X -> hi (k,v,q) + lo (k,q)
  split_x<<<dim3(8192, 1, 3), 256, 0, stream>>>(Xk, Xv, Xq, XH, XL);
  // 2) W -> W^T hi (K,V,Q) + lo (K,Q)
  transpose_split_w<<<dim3(32, 32, 3), 256, 0, stream>>>(WK, WV, WQ, WTH, WTL);
  // 3) V projection: V = XH[v] @ WTH[V]^T  (M=8192,N=1024,K=1024)
  gemm256<1, 128><<<dim3(8, 32, 1), 512, 98304, stream>>>(
      XH + MK, XH + MK, XH + MK, 0, 0, 0,
      WTH + WSZ, WTH + WSZ, WTH + WSZ, 0, 0, 0,
      V, nullptr, 0, 1024, 1024, 1, 1.0f);
  // 4) K,Q projections (3 terms, split hi/lo out): z=0 -> K, z=1 -> Q
  gemm256<2, 256><<<dim3(4, 32, 2), 512, 131072, stream>>>(
      XH, XH, XL, 2 * MK, 2 * MK, MK,
      WTH, WTL, WTH, 2 * WSZ, WSZ, 2 * WSZ,
      KH, KL, 2 * MK, 1024, 1024, 3, 1.0f);
  // 5) V^T per batch
  transpose_v<<<dim3(32, 64, 4), 256, 0, stream>>>(V, VT);
  // 6) scores[b] = Q[b]@K[b]^T / sqrt(2048)  (3 terms, fp32 out)
  gemm256<0, 256><<<dim3(8, 8, 4), 512, 131072, stream>>>(
      QH, QH, QL, S21, S21, S21,
      KH, KL, KH, S21, S21, S21,
      SCORES, nullptr, (size_t)2048 * 2048, 2048, 1024, 3,
      0.022097086912079608f);
  // 7) softmax -> P bf16
  softmax_rows<<<dim3(8192), 256, 0, stream>>>(SCORES, P);
  // 8) out[b] = P[b] @ VT[b]^T  (M=2048,N=1024,K=2048)
  gemm256<0, 128><<<dim3(8, 8, 4), 512, 98304, stream>>>(
      P, P, P, (size_t)2048 * 2048, 0, 0,
      VT, VT, VT, (size_t)1024 * 2048, 0, 0,
      out, nullptr, (size_t)2048 * 1024, 1024, 2048, 1, 1.0f);
}

// Round 5
// 310.927 us; speedup vs baseline: 1.2239x; 1.1187x over previous
//
#include <hip/hip_runtime.h>
#include <hip/hip_bf16.h>

// ---------------------------------------------------------------------------
// AttentionHead B=4,S=2048,D=1024. Split-bf16 (hi+lo) Q/K path, 3-term MFMA.
// gemm_f3: term-FUSED 256x256 GEMM (stage AH/AL/BH/BL once per K-tile, 6-phase
// m201-style schedule, double-buffered LDS, XCD-chunked block swizzle).
// gemm256: single-term 256x128 GEMM (4-deep pipeline) for V-proj / PV.
// R4 fix: PV grid.y was 16 (OOB writes past d_out, M=2048 -> 8 tiles of 256).
// ws layout identical to round-2 (high-water 186 MiB).
// ---------------------------------------------------------------------------

typedef __attribute__((ext_vector_type(4))) float  f32x4;
typedef __attribute__((ext_vector_type(8))) __bf16 bf16x8;
typedef __attribute__((ext_vector_type(4))) __bf16 bf16x4;

constexpr size_t MiB = 1u << 20;
constexpr size_t MK  = (size_t)8192 * 1024;
constexpr size_t WSZ = (size_t)1024 * 1024;

__device__ __forceinline__ void gload_lds16(const void* g, void* l) {
  __builtin_amdgcn_global_load_lds(
      (const __attribute__((address_space(1))) unsigned int*)g,
      (__attribute__((address_space(3))) unsigned int*)l, 16, 0, 0);
}

#define MFMA16(a, b, c) __builtin_amdgcn_mfma_f32_16x16x32_bf16(a, b, c, 0, 0, 0)

// XCD-chunked bijective block swizzle (requires total blocks % 8 == 0).
__device__ __forceinline__ void swz_block(int& bx, int& by, int& bz) {
  unsigned gx = gridDim.x, gy = gridDim.y;
  unsigned flat = blockIdx.x + gx * (blockIdx.y + gy * blockIdx.z);
  unsigned total = gx * gy * gridDim.z;
  unsigned cpx = total >> 3;
  unsigned s = (flat & 7) * cpx + (flat >> 3);
  bx = s % gx; s /= gx; by = s % gy; bz = s / gy;
}

// ---------------------------------------------------------------------------
__global__ __launch_bounds__(256) void split_x(
    const float* __restrict__ x0, const float* __restrict__ x1,
    const float* __restrict__ x2, __bf16* __restrict__ XH,
    __bf16* __restrict__ XL)
{
  const int z = blockIdx.z;
  const float* x = z == 0 ? x0 : (z == 1 ? x1 : x2);
  size_t i = ((size_t)blockIdx.x * 256 + threadIdx.x) * 4;
  float4 v = *(const float4*)(x + i);
  bf16x4 h = {(__bf16)v.x, (__bf16)v.y, (__bf16)v.z, (__bf16)v.w};
  *(bf16x4*)(XH + (size_t)z * MK + i) = h;
  if (z != 1) {
    bf16x4 l = {(__bf16)(v.x - (float)h[0]), (__bf16)(v.y - (float)h[1]),
                (__bf16)(v.z - (float)h[2]), (__bf16)(v.w - (float)h[3])};
    *(bf16x4*)(XL + (size_t)(z == 0 ? 0 : 1) * MK + i) = l;
  }
}

// ---------------------------------------------------------------------------
__global__ __launch_bounds__(256) void transpose_split_w(
    const float* __restrict__ w0, const float* __restrict__ w1,
    const float* __restrict__ w2, __bf16* __restrict__ WTH,
    __bf16* __restrict__ WTL)
{
  const int z = blockIdx.z;
  const float* W = z == 0 ? w0 : (z == 1 ? w1 : w2);
  __bf16* oh = WTH + (size_t)z * WSZ;
  __bf16* ol = WTL + (size_t)(z == 0 ? 0 : 1) * WSZ;
  __shared__ float tile[32][33];
  const int bx = blockIdx.x * 32;
  const int by = blockIdx.y * 32;
  const int tx = threadIdx.x & 31, ty = threadIdx.x >> 5;
  #pragma unroll
  for (int r = 0; r < 32; r += 8)
    tile[ty + r][tx] = W[(size_t)(by + ty + r) * 1024 + bx + tx];
  __syncthreads();
  #pragma unroll
  for (int r = 0; r < 32; r += 8) {
    float w = tile[tx][ty + r];
    __bf16 h = (__bf16)w;
    oh[(size_t)(bx + ty + r) * 1024 + by + tx] = h;
    if (z != 1)
      ol[(size_t)(bx + ty + r) * 1024 + by + tx] = (__bf16)(w - (float)h);
  }
}

// ---------------------------------------------------------------------------
__global__ __launch_bounds__(256) void transpose_v(
    const __bf16* __restrict__ V, __bf16* __restrict__ Vt)
{
  const __bf16* v = V + (size_t)blockIdx.z * 2048 * 1024;
  __bf16* o = Vt + (size_t)blockIdx.z * 1024 * 2048;
  __shared__ __bf16 tile[32][33];
  const int bx = blockIdx.x * 32;
  const int by = blockIdx.y * 32;
  const int tx = threadIdx.x & 31, ty = threadIdx.x >> 5;
  #pragma unroll
  for (int r = 0; r < 32; r += 8)
    tile[ty + r][tx] = v[(size_t)(by + ty + r) * 1024 + bx + tx];
  __syncthreads();
  #pragma unroll
  for (int r = 0; r < 32; r += 8)
    o[(size_t)(bx + ty + r) * 2048 + by + tx] = tile[tx][ty + r];
}

// ---------------------------------------------------------------------------
// gemm_f3: C = scale*(AH*BH^T + AH*BL^T + AL*BH^T), tile 256x256, BK=32,
// 8 waves (2Mx4N, per-wave 128x64). Term-fused staging: one K-tile stages
// AH/AL/BH/BL panels [256][32] once; 96 MFMA/wave against them in 6 phases.
// Phase = {ds_reads; (P0: stage 8 gloads); barrier; lgkmcnt(0); setprio(1);
// 16 MFMA; setprio(0); barrier}. Boundary vmcnt(0) sits ~5 phases after issue.
// LDS: 2 x 64KiB buffers; panels AH@0 AL@16K BH@32K BL@48K, swizzled
// (colbyte ^= ((row>>1)&3)<<4, applied on global src + ds_read addr).
// MODE 0: f32*scale -> C0 ; 2: hi/lo bf16 split -> C0,C1.
template <int MODE>
__global__ __launch_bounds__(512, 2) void gemm_f3(
    const __bf16* __restrict__ AHp, size_t sAH,
    const __bf16* __restrict__ ALp, size_t sAL,
    const __bf16* __restrict__ BHp, size_t sBH,
    const __bf16* __restrict__ BLp, size_t sBL,
    void* __restrict__ C0v, void* __restrict__ C1v, size_t sCz,
    int N, int K, float scale)
{
  extern __shared__ char lds[];
  int bx, by, bz;
  swz_block(bx, by, bz);

  const __bf16* AH = AHp + (size_t)bz * sAH;
  const __bf16* AL = ALp + (size_t)bz * sAL;
  const __bf16* BH = BHp + (size_t)bz * sBH;
  const __bf16* BL = BLp + (size_t)bz * sBL;

  const int gm0 = by * 256;
  const int gn0 = bx * 256;
  const int tid = threadIdx.x;
  const int lane = tid & 63, wave = tid >> 6;
  const int wm = (wave >> 2) * 128;
  const int wn = (wave & 3) * 64;
  const int fr = lane & 15, fq = lane >> 4;

  // staging: thread t -> row tid>>2 (and +128), swizzled source col
  const int cbs = (((tid & 3) ^ ((tid >> 3) & 3)) << 4);
  const size_t aOff = (size_t)(gm0 + (tid >> 2)) * K + (cbs >> 1);
  const size_t bOff = (size_t)(gn0 + (tid >> 2)) * K + (cbs >> 1);
  const size_t rs128 = (size_t)128 * K;
  const int dl = tid * 16;

  // fragment read offsets (swizzled), row stride 64B, 16-row tile = 1024B
  const int cbr  = (fq * 16) ^ (((fr >> 1) & 3) << 4);
  const int arow = (wm + fr) * 64 + cbr;
  const int brow = (wn + fr) * 64 + cbr;

  // running stage pointers (advance 32 elems/tile)
  const __bf16* pAH = AH + aOff;
  const __bf16* pAL = AL + aOff;
  const __bf16* pBH = BH + bOff;
  const __bf16* pBL = BL + bOff;

  f32x4 acc[8][4] = {};

  auto STAGE = [&](char* dst) {
    gload_lds16(pBH,         dst + 32768 + dl);
    gload_lds16(pBH + rs128, dst + 40960 + dl);
    gload_lds16(pAH,         dst + 0     + dl);
    gload_lds16(pAH + rs128, dst + 8192  + dl);
    gload_lds16(pBL,         dst + 49152 + dl);
    gload_lds16(pBL + rs128, dst + 57344 + dl);
    gload_lds16(pAL,         dst + 16384 + dl);
    gload_lds16(pAL + rs128, dst + 24576 + dl);
    pAH += 32; pAL += 32; pBH += 32; pBL += 32;
  };

  // prologue: stage tile 0
  STAGE(lds);
  asm volatile("s_waitcnt vmcnt(0)" ::: "memory");
  __builtin_amdgcn_s_barrier();
  __builtin_amdgcn_sched_barrier(0);

  const int nkt = K >> 5;

#define PHASE_PRE                                          \
  __builtin_amdgcn_s_barrier();                            \
  asm volatile("s_waitcnt lgkmcnt(0)" ::: "memory");       \
  __builtin_amdgcn_sched_barrier(0);                       \
  __builtin_amdgcn_s_setprio(1);
#define PHASE_POST                                         \
  __builtin_amdgcn_s_setprio(0);                           \
  __builtin_amdgcn_sched_barrier(0);                       \
  __builtin_amdgcn_s_barrier();

  for (int t = 0; t < nkt; ++t) {
    const char* buf  = lds + (t & 1) * 65536;
    char*       nbuf = lds + ((t + 1) & 1) * 65536;
    const bool st = (t + 1) < nkt;
    bf16x8 bh[4], bl[4], af[4];

    // ---- P0: read bh + ah_lo; stage next tile; MFMA ah_lo*bh -> acc[0..3]
    #pragma unroll
    for (int n = 0; n < 4; ++n) bh[n] = *(const bf16x8*)(buf + 32768 + brow + n * 1024);
    #pragma unroll
    for (int m = 0; m < 4; ++m) af[m] = *(const bf16x8*)(buf + 0 + arow + m * 1024);
    if (st) STAGE(nbuf);
    PHASE_PRE
    #pragma unroll
    for (int m = 0; m < 4; ++m)
      #pragma unroll
      for (int n = 0; n < 4; ++n) acc[m][n] = MFMA16(af[m], bh[n], acc[m][n]);
    PHASE_POST

    // ---- P1: read bl; MFMA ah_lo*bl
    #pragma unroll
    for (int n = 0; n < 4; ++n) bl[n] = *(const bf16x8*)(buf + 49152 + brow + n * 1024);
    PHASE_PRE
    #pragma unroll
    for (int m = 0; m < 4; ++m)
      #pragma unroll
      for (int n = 0; n < 4; ++n) acc[m][n] = MFMA16(af[m], bl[n], acc[m][n]);
    PHASE_POST

    // ---- P2: read al_lo; MFMA al_lo*bh
    #pragma unroll
    for (int m = 0; m < 4; ++m) af[m] = *(const bf16x8*)(buf + 16384 + arow + m * 1024);
    PHASE_PRE
    #pragma unroll
    for (int m = 0; m < 4; ++m)
      #pragma unroll
      for (int n = 0; n < 4; ++n) acc[m][n] = MFMA16(af[m], bh[n], acc[m][n]);
    PHASE_POST

    // ---- P3: read ah_hi; MFMA ah_hi*bh -> acc[4..7]
    #pragma unroll
    for (int m = 0; m < 4; ++m) af[m] = *(const bf16x8*)(buf + 0 + arow + (m + 4) * 1024);
    PHASE_PRE
    #pragma unroll
    for (int m = 0; m < 4; ++m)
      #pragma unroll
      for (int n = 0; n < 4; ++n) acc[m + 4][n] = MFMA16(af[m], bh[n], acc[m + 4][n]);
    PHASE_POST

    // ---- P4: read al_hi; MFMA ah_hi*bl
    bf16x8 alh[4];
    #pragma unroll
    for (int m = 0; m < 4; ++m) alh[m] = *(const bf16x8*)(buf + 16384 + arow + (m + 4) * 1024);
    PHASE_PRE
    #pragma unroll
    for (int m = 0; m < 4; ++m)
      #pragma unroll
      for (int n = 0; n < 4; ++n) acc[m + 4][n] = MFMA16(af[m], bl[n], acc[m + 4][n]);
    PHASE_POST

    // ---- P5: MFMA al_hi*bh; boundary vmcnt before trailing barrier
    __builtin_amdgcn_s_barrier();
    asm volatile("s_waitcnt lgkmcnt(0)" ::: "memory");
    __builtin_amdgcn_sched_barrier(0);
    __builtin_amdgcn_s_setprio(1);
    #pragma unroll
    for (int m = 0; m < 4; ++m)
      #pragma unroll
      for (int n = 0; n < 4; ++n) acc[m + 4][n] = MFMA16(alh[m], bh[n], acc[m + 4][n]);
    __builtin_amdgcn_s_setprio(0);
    __builtin_amdgcn_sched_barrier(0);
    asm volatile("s_waitcnt vmcnt(0)" ::: "memory");
    __builtin_amdgcn_s_barrier();
  }
#undef PHASE_PRE
#undef PHASE_POST

  // epilogue: C/D layout col=fr, row=fq*4+r
  const int erow = gm0 + wm + fq * 4;
  const int ecol = gn0 + wn + fr;
  if constexpr (MODE == 0) {
    float* C = (float*)C0v + (size_t)bz * sCz;
    #pragma unroll
    for (int m = 0; m < 8; ++m)
      #pragma unroll
      for (int n = 0; n < 4; ++n) {
        size_t base = (size_t)(erow + m * 16) * N + (ecol + n * 16);
        #pragma unroll
        for (int r = 0; r < 4; ++r)
          C[base + (size_t)r * N] = acc[m][n][r] * scale;
      }
  } else {
    __bf16* CH = (__bf16*)C0v + (size_t)bz * sCz;
    __bf16* CL = (__bf16*)C1v + (size_t)bz * sCz;
    #pragma unroll
    for (int m = 0; m < 8; ++m)
      #pragma unroll
      for (int n = 0; n < 4; ++n) {
        size_t base = (size_t)(erow + m * 16) * N + (ecol + n * 16);
        #pragma unroll
        for (int r = 0; r < 4; ++r) {
          float v = acc[m][n][r];
          __bf16 h = (__bf16)v;
          CH[base + (size_t)r * N] = h;
          CL[base + (size_t)r * N] = (__bf16)(v - (float)h);
        }
      }
  }
}

// ---------------------------------------------------------------------------
// gemm256: single-term bt GEMM, tile 256x128, BK=32, 4-deep pipeline.
// MODE 0: f32*scale ; 1: bf16.
template <int MODE>
__global__ __launch_bounds__(512, 2) void gemm256(
    const __bf16* __restrict__ At, size_t sA,
    const __bf16* __restrict__ Bt, size_t sB,
    void* __restrict__ C0v, size_t sCz,
    int N, int K, float scale)
{
  extern __shared__ char lds[];
  constexpr int BB = 128 * 64;
  char* ldsAb = lds;             // 4 x 16384
  char* ldsBb = lds + 65536;     // 4 x 8192

  int bx, by, bz;
  swz_block(bx, by, bz);
  const __bf16* A = At + (size_t)bz * sA;
  const __bf16* B = Bt + (size_t)bz * sB;

  const int gm0 = by * 256;
  const int gn0 = bx * 128;
  const int tid = threadIdx.x;
  const int lane = tid & 63, wave = tid >> 6;
  const int wm = (wave >> 1) * 64;
  const int wn = (wave & 1) * 64;
  const int fr = lane & 15, fq = lane >> 4;

  const int nkt = K >> 5;

  const int cbs = (((tid & 3) ^ ((tid >> 3) & 3)) << 4);
  const size_t aOff = (size_t)(gm0 + (tid >> 2)) * K + (cbs >> 1);
  const size_t bOff = (size_t)(gn0 + (tid >> 2)) * K + (cbs >> 1);
  const int cbr  = (fq * 16) ^ (((fr >> 1) & 3) << 4);
  const int arow = (wm + fr) * 64 + cbr;
  const int brow = (wn + fr) * 64 + cbr;

  f32x4 acc[4][4] = {};

  for (int tp = 0; tp < 3; ++tp) {
    const __bf16* gA = A + aOff + tp * 32;
    const __bf16* gB = B + bOff + tp * 32;
    char* dA = ldsAb + tp * 16384 + tid * 16;
    char* dB = ldsBb + tp * BB + tid * 16;
    gload_lds16(gA, dA);
    gload_lds16(gA + (size_t)128 * K, dA + 8192);
    gload_lds16(gB, dB);
  }
  asm volatile("s_waitcnt vmcnt(6)" ::: "memory");
  __builtin_amdgcn_s_barrier();
  __builtin_amdgcn_sched_barrier(0);

  for (int t = 0; t < nkt; ++t) {
    const char* pA = ldsAb + (t & 3) * 16384;
    const char* pB = ldsBb + (t & 3) * BB;
    const int tp = t + 3;
    const bool st = tp < nkt;
    const __bf16* gA = A + aOff + (st ? tp : 0) * 32;
    const __bf16* gB = B + bOff + (st ? tp : 0) * 32;
    char* dA = ldsAb + (tp & 3) * 16384 + tid * 16;
    char* dB = ldsBb + (tp & 3) * BB + tid * 16;

    if (st) { gload_lds16(gA, dA); gload_lds16(gB, dB); }
    bf16x8 bfr[4], af[2];
    #pragma unroll
    for (int n = 0; n < 4; ++n) bfr[n] = *(const bf16x8*)(pB + brow + n * 1024);
    #pragma unroll
    for (int m = 0; m < 2; ++m) af[m] = *(const bf16x8*)(pA + arow + m * 1024);
    __builtin_amdgcn_s_setprio(1);
    #pragma unroll
    for (int m = 0; m < 2; ++m)
      #pragma unroll
      for (int n = 0; n < 4; ++n) acc[m][n] = MFMA16(af[m], bfr[n], acc[m][n]);
    __builtin_amdgcn_s_setprio(0);
    __builtin_amdgcn_s_barrier();
    __builtin_amdgcn_sched_barrier(0);

    if (st) gload_lds16(gA + (size_t)128 * K, dA + 8192);
    #pragma unroll
    for (int m = 0; m < 2; ++m) af[m] = *(const bf16x8*)(pA + arow + (m + 2) * 1024);
    __builtin_amdgcn_s_setprio(1);
    #pragma unroll
    for (int m = 0; m < 2; ++m)
      #pragma unroll
      for (int n = 0; n < 4; ++n) acc[m + 2][n] = MFMA16(af[m], bfr[n], acc[m + 2][n]);
    __builtin_amdgcn_s_setprio(0);
    asm volatile("s_waitcnt vmcnt(6)" ::: "memory");
    __builtin_amdgcn_s_barrier();
    __builtin_amdgcn_sched_barrier(0);
  }

  const int erow = gm0 + wm + fq * 4;
  const int ecol = gn0 + wn + fr;
  if constexpr (MODE == 0) {
    float* C = (float*)C0v + (size_t)bz * sCz;
    #pragma unroll
    for (int m = 0; m < 4; ++m)
      #pragma unroll
      for (int n = 0; n < 4; ++n) {
        size_t base = (size_t)(erow + m * 16) * N + (ecol + n * 16);
        #pragma unroll
        for (int r = 0; r < 4; ++r)
          C[base + (size_t)r * N] = acc[m][n][r] * scale;
      }
  } else {
    __bf16* C = (__bf16*)C0v + (size_t)bz * sCz;
    #pragma unroll
    for (int m = 0; m < 4; ++m)
      #pragma unroll
      for (int n = 0; n < 4; ++n) {
        size_t base = (size_t)(erow + m * 16) * N + (ecol + n * 16);
        #pragma unroll
        for (int r = 0; r < 4; ++r)
          C[base + (size_t)r * N] = (__bf16)acc[m][n][r];
      }
  }
}

// ---------------------------------------------------------------------------
__global__ __launch_bounds__(256) void softmax_rows(
    const float* __restrict__ S, __bf16* __restrict__ P)
{
  const size_t row = blockIdx.x;
  const float4* srow = (const float4*)(S + row * 2048);
  const int t = threadIdx.x;
  float4 v0 = srow[t];
  float4 v1 = srow[t + 256];

  float m = fmaxf(fmaxf(fmaxf(v0.x, v0.y), fmaxf(v0.z, v0.w)),
                  fmaxf(fmaxf(v1.x, v1.y), fmaxf(v1.z, v1.w)));
  #pragma unroll
  for (int o = 32; o >= 1; o >>= 1) m = fmaxf(m, __shfl_xor(m, o));
  __shared__ float redm[4];
  if ((t & 63) == 0) redm[t >> 6] = m;
  __syncthreads();
  m = fmaxf(fmaxf(redm[0], redm[1]), fmaxf(redm[2], redm[3]));

  float e[8];
  e[0] = __expf(v0.x - m); e[1] = __expf(v0.y - m);
  e[2] = __expf(v0.z - m); e[3] = __expf(v0.w - m);
  e[4] = __expf(v1.x - m); e[5] = __expf(v1.y - m);
  e[6] = __expf(v1.z - m); e[7] = __expf(v1.w - m);
  float s = e[0] + e[1] + e[2] + e[3] + e[4] + e[5] + e[6] + e[7];
  #pragma unroll
  for (int o = 32; o >= 1; o >>= 1) s += __shfl_xor(s, o);
  __shared__ float reds[4];
  if ((t & 63) == 0) reds[t >> 6] = s;
  __syncthreads();
  s = reds[0] + reds[1] + reds[2] + reds[3];

  const float inv = 1.0f / s;
  bf16x4 p0 = {(__bf16)(e[0] * inv), (__bf16)(e[1] * inv),
               (__bf16)(e[2] * inv), (__bf16)(e[3] * inv)};
  bf16x4 p1 = {(__bf16)(e[4] * inv), (__bf16)(e[5] * inv),
               (__bf16)(e[6] * inv), (__bf16)(e[7] * inv)};
  bf16x4* prow = (bf16x4*)(P + row * 2048);
  prow[t] = p0;
  prow[t + 256] = p1;
}

// ---------------------------------------------------------------------------
extern "C" void kernel_launch(void* const* d_in, const int* in_sizes, int n_in,
                              void* d_out, int out_size, void* d_ws, size_t ws_size,
                              hipStream_t stream)
{
  const float* Xk = (const float*)d_in[0];
  const float* Xv = (const float*)d_in[1];
  const float* Xq = (const float*)d_in[2];
  const float* WK = (const float*)d_in[3];
  const float* WV = (const float*)d_in[4];
  const float* WQ = (const float*)d_in[5];
  float* out = (float*)d_out;
  char* ws = (char*)d_ws;

  __bf16* XH  = (__bf16*)(ws);               // 0..48 MiB
  __bf16* XL  = (__bf16*)(ws + 48 * MiB);    // 48..80 (k,q)
  __bf16* WTH = (__bf16*)(ws + 80 * MiB);
  __bf16* WTL = (__bf16*)(ws + 86 * MiB);
  __bf16* KH  = (__bf16*)(ws + 90 * MiB);
  __bf16* KL  = (__bf16*)(ws + 106 * MiB);
  __bf16* QH  = (__bf16*)(ws + 122 * MiB);
  __bf16* QL  = (__bf16*)(ws + 138 * MiB);
  __bf16* V   = (__bf16*)(ws + 154 * MiB);
  __bf16* VT  = (__bf16*)(ws + 170 * MiB);   // ..186
  float*  SCORES = (float*)(ws);             // alias XH+XLk (dead post-proj)
  __bf16* P   = (__bf16*)(ws + 64 * MiB);    // alias (dead post-scores)

  const size_t S21 = (size_t)2048 * 1024;

  auto* fKQ = gemm_f3<2>;
  auto* fSC = gemm_f3<0>;
  auto* fV  = gemm256<1>;
  auto* fPV = gemm256<0>;
  (void)hipFuncSetAttribute((const void*)fKQ, hipFuncAttributeMaxDynamicSharedMemorySize, 131072);
  (void)hipFuncSetAttribute((const void*)fSC, hipFuncAttributeMaxDynamicSharedMemorySize, 131072);
  (void)hipFuncSetAttribute((const void*)fV,  hipFuncAttributeMaxDynamicSharedMemorySize, 98304);
  (void)hipFuncSetAttribute((const void*)fPV, hipFuncAttributeMaxDynamicSharedMemorySize, 98304);

  // 1) split X -> hi (k,v,q) + lo (k,q)
  split_x<<<dim3(8192, 1, 3), 256, 0, stream>>>(Xk, Xv, Xq, XH, XL);
  // 2) W -> W^T hi (K,V,Q) + lo (K,Q)
  transpose_split_w<<<dim3(32, 32, 3), 256, 0, stream>>>(WK, WV, WQ, WTH, WTL);
  // 3) V projection: V = XH[v] @ WTH[V]^T  (M=8192,N=1024,K=1024)
  gemm256<1><<<dim3(8, 32, 1), 512, 98304, stream>>>(
      XH + MK, 0, WTH + WSZ, 0, V, 0, 1024, 1024, 1.0f);
  // 4) K,Q projections (term-fused split3): z=0 -> K, z=1 -> Q
  gemm_f3<2><<<dim3(4, 32, 2), 512, 131072, stream>>>(
      XH, 2 * MK, XL, MK, WTH, 2 * WSZ, WTL, WSZ,
      KH, KL, 2 * MK, 1024, 1024, 1.0f);
  // 5) V^T per batch
  transpose_v<<<dim3(32, 64, 4), 256, 0, stream>>>(V, VT);
  // 6) scores[b] = Q[b]@K[b]^T / sqrt(2048)  (term-fused split3)
  gemm_f3<0><<<dim3(8, 8, 4), 512, 131072, stream>>>(
      QH, S21, QL, S21, KH, S21, KL, S21,
      SCORES, nullptr, (size_t)2048 * 2048, 2048, 1024,
      0.022097086912079608f);
  // 7) softmax -> P bf16
  softmax_rows<<<dim3(8192), 256, 0, stream>>>(SCORES, P);
  // 8) out[b] = P[b] @ VT[b]^T  (M=2048,N=1024,K=2048; 8 M-tiles of 256)
  gemm256<0><<<dim3(8, 8, 4), 512, 98304, stream>>>(
      P, (size_t)2048 * 2048, VT, (size_t)1024 * 2048,
      out, (size_t)2048 * 1024, 1024, 2048, 1.0f);
}

// Round 6
// 222.123 us; speedup vs baseline: 1.7132x; 1.3998x over previous
//
#include <hip/hip_runtime.h>
#include <hip/hip_bf16.h>

// ---------------------------------------------------------------------------
// AttentionHead B=4,S=2048,D=1024 — ALL-F16 pipeline (round 6).
// f16 (11-bit mantissa) makes every GEMM single-term: err chain ~0.07-0.12
// vs threshold 0.279. Total MFMA work 120 GF (was 258 GF with bf16 split-3).
// All GEMMs: gemm256 256x128 tile, BK=32, 4-deep LDS pipeline, counted vmcnt,
// T2 swizzle, T5 setprio, XCD-chunked block swizzle.
//
// ws layout (MiB): XF@0(48) WT@48(6) PROJ@54(48: K,V,Q) VT@102(16)
//                  SCORES@118(64,f32) P@0(32,f16, alias XF dead post-proj)
// high-water 182 MiB.
// ---------------------------------------------------------------------------

typedef __attribute__((ext_vector_type(4))) float    f32x4;
typedef __attribute__((ext_vector_type(8))) _Float16 f16x8;
typedef __attribute__((ext_vector_type(4))) _Float16 f16x4;

constexpr size_t MiB = 1u << 20;
constexpr size_t MK  = (size_t)8192 * 1024;
constexpr size_t WSZ = (size_t)1024 * 1024;

__device__ __forceinline__ void gload_lds16(const void* g, void* l) {
  __builtin_amdgcn_global_load_lds(
      (const __attribute__((address_space(1))) unsigned int*)g,
      (__attribute__((address_space(3))) unsigned int*)l, 16, 0, 0);
}

#define MFMA16(a, b, c) __builtin_amdgcn_mfma_f32_16x16x32_f16(a, b, c, 0, 0, 0)

// XCD-chunked bijective block swizzle (requires total blocks % 8 == 0).
__device__ __forceinline__ void swz_block(int& bx, int& by, int& bz) {
  unsigned gx = gridDim.x, gy = gridDim.y;
  unsigned flat = blockIdx.x + gx * (blockIdx.y + gy * blockIdx.z);
  unsigned total = gx * gy * gridDim.z;
  unsigned cpx = total >> 3;
  unsigned s = (flat & 7) * cpx + (flat >> 3);
  bx = s % gx; s /= gx; by = s % gy; bz = s / gy;
}

// ---------------------------------------------------------------------------
// X fp32 -> f16, 4 elems/thread; z selects input matrix (k,v,q).
__global__ __launch_bounds__(256) void convert_x(
    const float* __restrict__ x0, const float* __restrict__ x1,
    const float* __restrict__ x2, _Float16* __restrict__ XF)
{
  const int z = blockIdx.z;
  const float* x = z == 0 ? x0 : (z == 1 ? x1 : x2);
  size_t i = ((size_t)blockIdx.x * 256 + threadIdx.x) * 4;
  float4 v = *(const float4*)(x + i);
  f16x4 h = {(_Float16)v.x, (_Float16)v.y, (_Float16)v.z, (_Float16)v.w};
  *(f16x4*)(XF + (size_t)z * MK + i) = h;
}

// ---------------------------------------------------------------------------
// W [1024][1024] f32 -> WT [1024][1024] f16 transposed; z selects matrix.
__global__ __launch_bounds__(256) void transpose_conv_w(
    const float* __restrict__ w0, const float* __restrict__ w1,
    const float* __restrict__ w2, _Float16* __restrict__ WT)
{
  const int z = blockIdx.z;
  const float* W = z == 0 ? w0 : (z == 1 ? w1 : w2);
  _Float16* o = WT + (size_t)z * WSZ;
  __shared__ float tile[32][33];
  const int bx = blockIdx.x * 32;
  const int by = blockIdx.y * 32;
  const int tx = threadIdx.x & 31, ty = threadIdx.x >> 5;
  #pragma unroll
  for (int r = 0; r < 32; r += 8)
    tile[ty + r][tx] = W[(size_t)(by + ty + r) * 1024 + bx + tx];
  __syncthreads();
  #pragma unroll
  for (int r = 0; r < 32; r += 8)
    o[(size_t)(bx + ty + r) * 1024 + by + tx] = (_Float16)tile[tx][ty + r];
}

// ---------------------------------------------------------------------------
// V [z][2048][1024] f16 -> VT [z][1024][2048] f16
__global__ __launch_bounds__(256) void transpose_v(
    const _Float16* __restrict__ V, _Float16* __restrict__ Vt)
{
  const _Float16* v = V + (size_t)blockIdx.z * 2048 * 1024;
  _Float16* o = Vt + (size_t)blockIdx.z * 1024 * 2048;
  __shared__ _Float16 tile[32][33];
  const int bx = blockIdx.x * 32;   // e
  const int by = blockIdx.y * 32;   // s
  const int tx = threadIdx.x & 31, ty = threadIdx.x >> 5;
  #pragma unroll
  for (int r = 0; r < 32; r += 8)
    tile[ty + r][tx] = v[(size_t)(by + ty + r) * 1024 + bx + tx];
  __syncthreads();
  #pragma unroll
  for (int r = 0; r < 32; r += 8)
    o[(size_t)(bx + ty + r) * 2048 + by + tx] = tile[tx][ty + r];
}

// ---------------------------------------------------------------------------
// gemm256: C[m][n] = scale * sum_k A[m][k]*Bt[n][k], f16 inputs.
// Tile 256(M) x 128(N), BK=32, 512 thr (8 waves 4Mx2N, per-wave 64x64).
// 4-deep LDS pipeline: stage t+3 during t, boundary s_waitcnt vmcnt(6).
// T2 swizzle on staging source + ds_read addr. MODE 0: f32*scale; 1: f16.
template <int MODE>
__global__ __launch_bounds__(512, 2) void gemm256(
    const _Float16* __restrict__ At, size_t sA,
    const _Float16* __restrict__ Bt, size_t sB,
    void* __restrict__ C0v, size_t sCz,
    int N, int K, float scale)
{
  extern __shared__ char lds[];
  constexpr int BB = 128 * 64;
  char* ldsAb = lds;             // 4 x 16384
  char* ldsBb = lds + 65536;     // 4 x 8192

  int bx, by, bz;
  swz_block(bx, by, bz);
  const _Float16* A = At + (size_t)bz * sA;
  const _Float16* B = Bt + (size_t)bz * sB;

  const int gm0 = by * 256;
  const int gn0 = bx * 128;
  const int tid = threadIdx.x;
  const int lane = tid & 63, wave = tid >> 6;
  const int wm = (wave >> 1) * 64;
  const int wn = (wave & 1) * 64;
  const int fr = lane & 15, fq = lane >> 4;

  const int nkt = K >> 5;

  const int cbs = (((tid & 3) ^ ((tid >> 3) & 3)) << 4);
  const size_t aOff = (size_t)(gm0 + (tid >> 2)) * K + (cbs >> 1);
  const size_t bOff = (size_t)(gn0 + (tid >> 2)) * K + (cbs >> 1);
  const int cbr  = (fq * 16) ^ (((fr >> 1) & 3) << 4);
  const int arow = (wm + fr) * 64 + cbr;
  const int brow = (wn + fr) * 64 + cbr;

  f32x4 acc[4][4] = {};

  for (int tp = 0; tp < 3; ++tp) {
    const _Float16* gA = A + aOff + tp * 32;
    const _Float16* gB = B + bOff + tp * 32;
    char* dA = ldsAb + tp * 16384 + tid * 16;
    char* dB = ldsBb + tp * BB + tid * 16;
    gload_lds16(gA, dA);
    gload_lds16(gA + (size_t)128 * K, dA + 8192);
    gload_lds16(gB, dB);
  }
  asm volatile("s_waitcnt vmcnt(6)" ::: "memory");
  __builtin_amdgcn_s_barrier();
  __builtin_amdgcn_sched_barrier(0);

  for (int t = 0; t < nkt; ++t) {
    const char* pA = ldsAb + (t & 3) * 16384;
    const char* pB = ldsBb + (t & 3) * BB;
    const int tp = t + 3;
    const bool st = tp < nkt;
    const _Float16* gA = A + aOff + (st ? tp : 0) * 32;
    const _Float16* gB = B + bOff + (st ? tp : 0) * 32;
    char* dA = ldsAb + (tp & 3) * 16384 + tid * 16;
    char* dB = ldsBb + (tp & 3) * BB + tid * 16;

    if (st) { gload_lds16(gA, dA); gload_lds16(gB, dB); }
    f16x8 bfr[4], af[2];
    #pragma unroll
    for (int n = 0; n < 4; ++n) bfr[n] = *(const f16x8*)(pB + brow + n * 1024);
    #pragma unroll
    for (int m = 0; m < 2; ++m) af[m] = *(const f16x8*)(pA + arow + m * 1024);
    __builtin_amdgcn_s_setprio(1);
    #pragma unroll
    for (int m = 0; m < 2; ++m)
      #pragma unroll
      for (int n = 0; n < 4; ++n) acc[m][n] = MFMA16(af[m], bfr[n], acc[m][n]);
    __builtin_amdgcn_s_setprio(0);
    __builtin_amdgcn_s_barrier();
    __builtin_amdgcn_sched_barrier(0);

    if (st) gload_lds16(gA + (size_t)128 * K, dA + 8192);
    #pragma unroll
    for (int m = 0; m < 2; ++m) af[m] = *(const f16x8*)(pA + arow + (m + 2) * 1024);
    __builtin_amdgcn_s_setprio(1);
    #pragma unroll
    for (int m = 0; m < 2; ++m)
      #pragma unroll
      for (int n = 0; n < 4; ++n) acc[m + 2][n] = MFMA16(af[m], bfr[n], acc[m + 2][n]);
    __builtin_amdgcn_s_setprio(0);
    asm volatile("s_waitcnt vmcnt(6)" ::: "memory");
    __builtin_amdgcn_s_barrier();
    __builtin_amdgcn_sched_barrier(0);
  }

  // epilogue: C/D layout col=fr, row=fq*4+r
  const int erow = gm0 + wm + fq * 4;
  const int ecol = gn0 + wn + fr;
  if constexpr (MODE == 0) {
    float* C = (float*)C0v + (size_t)bz * sCz;
    #pragma unroll
    for (int m = 0; m < 4; ++m)
      #pragma unroll
      for (int n = 0; n < 4; ++n) {
        size_t base = (size_t)(erow + m * 16) * N + (ecol + n * 16);
        #pragma unroll
        for (int r = 0; r < 4; ++r)
          C[base + (size_t)r * N] = acc[m][n][r] * scale;
      }
  } else {
    _Float16* C = (_Float16*)C0v + (size_t)bz * sCz;
    #pragma unroll
    for (int m = 0; m < 4; ++m)
      #pragma unroll
      for (int n = 0; n < 4; ++n) {
        size_t base = (size_t)(erow + m * 16) * N + (ecol + n * 16);
        #pragma unroll
        for (int r = 0; r < 4; ++r)
          C[base + (size_t)r * N] = (_Float16)acc[m][n][r];
      }
  }
}

// ---------------------------------------------------------------------------
// Row softmax: scores [8192 rows][2048] f32 -> P f16.
__global__ __launch_bounds__(256) void softmax_rows(
    const float* __restrict__ S, _Float16* __restrict__ P)
{
  const size_t row = blockIdx.x;
  const float4* srow = (const float4*)(S + row * 2048);
  const int t = threadIdx.x;
  float4 v0 = srow[t];
  float4 v1 = srow[t + 256];

  float m = fmaxf(fmaxf(fmaxf(v0.x, v0.y), fmaxf(v0.z, v0.w)),
                  fmaxf(fmaxf(v1.x, v1.y), fmaxf(v1.z, v1.w)));
  #pragma unroll
  for (int o = 32; o >= 1; o >>= 1) m = fmaxf(m, __shfl_xor(m, o));
  __shared__ float redm[4];
  if ((t & 63) == 0) redm[t >> 6] = m;
  __syncthreads();
  m = fmaxf(fmaxf(redm[0], redm[1]), fmaxf(redm[2], redm[3]));

  float e[8];
  e[0] = __expf(v0.x - m); e[1] = __expf(v0.y - m);
  e[2] = __expf(v0.z - m); e[3] = __expf(v0.w - m);
  e[4] = __expf(v1.x - m); e[5] = __expf(v1.y - m);
  e[6] = __expf(v1.z - m); e[7] = __expf(v1.w - m);
  float s = e[0] + e[1] + e[2] + e[3] + e[4] + e[5] + e[6] + e[7];
  #pragma unroll
  for (int o = 32; o >= 1; o >>= 1) s += __shfl_xor(s, o);
  __shared__ float reds[4];
  if ((t & 63) == 0) reds[t >> 6] = s;
  __syncthreads();
  s = reds[0] + reds[1] + reds[2] + reds[3];

  const float inv = 1.0f / s;
  f16x4 p0 = {(_Float16)(e[0] * inv), (_Float16)(e[1] * inv),
              (_Float16)(e[2] * inv), (_Float16)(e[3] * inv)};
  f16x4 p1 = {(_Float16)(e[4] * inv), (_Float16)(e[5] * inv),
              (_Float16)(e[6] * inv), (_Float16)(e[7] * inv)};
  f16x4* prow = (f16x4*)(P + row * 2048);
  prow[t] = p0;
  prow[t + 256] = p1;
}

// ---------------------------------------------------------------------------
extern "C" void kernel_launch(void* const* d_in, const int* in_sizes, int n_in,
                              void* d_out, int out_size, void* d_ws, size_t ws_size,
                              hipStream_t stream)
{
  const float* Xk = (const float*)d_in[0];
  const float* Xv = (const float*)d_in[1];
  const float* Xq = (const float*)d_in[2];
  const float* WK = (const float*)d_in[3];
  const float* WV = (const float*)d_in[4];
  const float* WQ = (const float*)d_in[5];
  float* out = (float*)d_out;
  char* ws = (char*)d_ws;

  _Float16* XF  = (_Float16*)(ws);               // 0..48 MiB
  _Float16* WT  = (_Float16*)(ws + 48 * MiB);    // 48..54
  _Float16* PROJ= (_Float16*)(ws + 54 * MiB);    // 54..102 (K,V,Q)
  _Float16* VT  = (_Float16*)(ws + 102 * MiB);   // 102..118
  float*   SCORES = (float*)(ws + 118 * MiB);    // 118..182
  _Float16* P   = (_Float16*)(ws);               // alias XF (dead post-proj)

  _Float16* Kp = PROJ;
  _Float16* Vp = PROJ + MK;
  _Float16* Qp = PROJ + 2 * MK;

  auto* fP  = gemm256<1>;
  auto* fSC = gemm256<0>;
  (void)hipFuncSetAttribute((const void*)fP,  hipFuncAttributeMaxDynamicSharedMemorySize, 98304);
  (void)hipFuncSetAttribute((const void*)fSC, hipFuncAttributeMaxDynamicSharedMemorySize, 98304);

  // 1) X -> f16 (k,v,q)
  convert_x<<<dim3(8192, 1, 3), 256, 0, stream>>>(Xk, Xv, Xq, XF);
  // 2) W -> W^T f16 (K,V,Q)
  transpose_conv_w<<<dim3(32, 32, 3), 256, 0, stream>>>(WK, WV, WQ, WT);
  // 3) projections batched: PROJ[z] = XF[z] @ WT[z]^T  (M=8192,N=1024,K=1024)
  gemm256<1><<<dim3(8, 32, 3), 512, 98304, stream>>>(
      XF, MK, WT, WSZ, PROJ, MK, 1024, 1024, 1.0f);
  // 4) V^T per batch
  transpose_v<<<dim3(32, 64, 4), 256, 0, stream>>>(Vp, VT);
  // 5) scores[b] = Q[b]@K[b]^T / sqrt(2048)  (M=2048,N=2048,K=1024)
  gemm256<0><<<dim3(16, 8, 4), 512, 98304, stream>>>(
      Qp, (size_t)2048 * 1024, Kp, (size_t)2048 * 1024,
      SCORES, (size_t)2048 * 2048, 2048, 1024, 0.022097086912079608f);
  // 6) softmax -> P f16
  softmax_rows<<<dim3(8192), 256, 0, stream>>>(SCORES, P);
  // 7) out[b] = P[b] @ VT[b]^T  (M=2048,N=1024,K=2048)
  gemm256<0><<<dim3(8, 8, 4), 512, 98304, stream>>>(
      P, (size_t)2048 * 2048, VT, (size_t)1024 * 2048,
      out, (size_t)2048 * 1024, 1024, 2048, 1.0f);
}

// Round 7
// 202.442 us; speedup vs baseline: 1.8797x; 1.0972x over previous
//
#include <hip/hip_runtime.h>
#include <hip/hip_bf16.h>

// ---------------------------------------------------------------------------
// AttentionHead B=4,S=2048,D=1024 — all-f16 pipeline, round 7.
// gemm8p: m201-style 256x256 BK=64 4-phase/K-tile schedule (counted vmcnt(2),
//         T2 8-chunk XOR swizzle, T5 setprio) for projections + scores.
// gemm256: round-6 proven 256x128 4-deep kernel for PV.
// scores stored f16; softmax wave-per-row (no LDS reduce).
// ws (MiB): XF@0(48) WT@48(6) PROJ@54(48) VT@102(16) SCORES@118(32,f16)
//           P@0(32,f16, alias XF dead post-proj). high-water 150 MiB.
// ---------------------------------------------------------------------------

typedef __attribute__((ext_vector_type(4))) float    f32x4;
typedef __attribute__((ext_vector_type(8))) _Float16 f16x8;
typedef __attribute__((ext_vector_type(4))) _Float16 f16x4;

constexpr size_t MiB = 1u << 20;
constexpr size_t MK  = (size_t)8192 * 1024;
constexpr size_t WSZ = (size_t)1024 * 1024;

__device__ __forceinline__ void gload_lds16(const void* g, void* l) {
  __builtin_amdgcn_global_load_lds(
      (const __attribute__((address_space(1))) unsigned int*)g,
      (__attribute__((address_space(3))) unsigned int*)l, 16, 0, 0);
}

#define MFMA16(a, b, c) __builtin_amdgcn_mfma_f32_16x16x32_f16(a, b, c, 0, 0, 0)

// XCD-chunked bijective block swizzle (requires total blocks % 8 == 0).
__device__ __forceinline__ void swz_block(int& bx, int& by, int& bz) {
  unsigned gx = gridDim.x, gy = gridDim.y;
  unsigned flat = blockIdx.x + gx * (blockIdx.y + gy * blockIdx.z);
  unsigned total = gx * gy * gridDim.z;
  unsigned cpx = total >> 3;
  unsigned s = (flat & 7) * cpx + (flat >> 3);
  bx = s % gx; s /= gx; by = s % gy; bz = s / gy;
}

// ---------------------------------------------------------------------------
__global__ __launch_bounds__(256) void convert_x(
    const float* __restrict__ x0, const float* __restrict__ x1,
    const float* __restrict__ x2, _Float16* __restrict__ XF)
{
  const int z = blockIdx.z;
  const float* x = z == 0 ? x0 : (z == 1 ? x1 : x2);
  size_t i = ((size_t)blockIdx.x * 256 + threadIdx.x) * 4;
  float4 v = *(const float4*)(x + i);
  f16x4 h = {(_Float16)v.x, (_Float16)v.y, (_Float16)v.z, (_Float16)v.w};
  *(f16x4*)(XF + (size_t)z * MK + i) = h;
}

// ---------------------------------------------------------------------------
__global__ __launch_bounds__(256) void transpose_conv_w(
    const float* __restrict__ w0, const float* __restrict__ w1,
    const float* __restrict__ w2, _Float16* __restrict__ WT)
{
  const int z = blockIdx.z;
  const float* W = z == 0 ? w0 : (z == 1 ? w1 : w2);
  _Float16* o = WT + (size_t)z * WSZ;
  __shared__ float tile[32][33];
  const int bx = blockIdx.x * 32;
  const int by = blockIdx.y * 32;
  const int tx = threadIdx.x & 31, ty = threadIdx.x >> 5;
  #pragma unroll
  for (int r = 0; r < 32; r += 8)
    tile[ty + r][tx] = W[(size_t)(by + ty + r) * 1024 + bx + tx];
  __syncthreads();
  #pragma unroll
  for (int r = 0; r < 32; r += 8)
    o[(size_t)(bx + ty + r) * 1024 + by + tx] = (_Float16)tile[tx][ty + r];
}

// ---------------------------------------------------------------------------
__global__ __launch_bounds__(256) void transpose_v(
    const _Float16* __restrict__ V, _Float16* __restrict__ Vt)
{
  const _Float16* v = V + (size_t)blockIdx.z * 2048 * 1024;
  _Float16* o = Vt + (size_t)blockIdx.z * 1024 * 2048;
  __shared__ _Float16 tile[32][33];
  const int bx = blockIdx.x * 32;   // e
  const int by = blockIdx.y * 32;   // s
  const int tx = threadIdx.x & 31, ty = threadIdx.x >> 5;
  #pragma unroll
  for (int r = 0; r < 32; r += 8)
    tile[ty + r][tx] = v[(size_t)(by + ty + r) * 1024 + bx + tx];
  __syncthreads();
  #pragma unroll
  for (int r = 0; r < 32; r += 8)
    o[(size_t)(bx + ty + r) * 2048 + by + tx] = tile[tx][ty + r];
}

// ---------------------------------------------------------------------------
// gemm8p: C[m][n] = scale * sum_k A[m][k]*Bt[n][k]  (m201-ported schedule)
// 256x256 tile, BK=64, 512 thr = 8 waves (2M x 4N; per-wave 128x64).
// LDS 2 x 64KiB dbuf: A [256][64] @0, B [256][64] @32768; rows 128B;
// swizzle: phys_chunk16B = logical ^ (row&7)  (source-side + ds_read).
// 4 phases/K-tile: {12 ds_read | 4 | 8 | 0} reads, stage half-tile of t+1
// (h1,h2,h3) in P0..P2, h0(t+2) in P3; boundary vmcnt(2) (0 only in tail).
// MODE 0: f32*scale ; 1: f16 ; 2: f16*scale.
template <int MODE>
__global__ __launch_bounds__(512, 2) void gemm8p(
    const _Float16* __restrict__ At, size_t sA,
    const _Float16* __restrict__ Bt, size_t sB,
    void* __restrict__ Cv, size_t sCz,
    int N, int K, float scale)
{
  extern __shared__ char lds[];
  int bx, by, bz;
  swz_block(bx, by, bz);
  const _Float16* A = At + (size_t)bz * sA;
  const _Float16* B = Bt + (size_t)bz * sB;

  const int gm0 = by * 256, gn0 = bx * 256;
  const int tid = threadIdx.x;
  const int lane = tid & 63, wave = tid >> 6;
  const int wm = (wave >> 2) * 128;   // 2 M groups of 128
  const int wn = (wave & 3) * 64;     // 4 N groups of 64
  const int fr = lane & 15, fq = lane >> 4;
  const int nkt = K >> 6;

  // ---- staging: thread t loads 16B x2 per half-tile (16KB each).
  // dest byte (in half) = tid*16 + l*8192 -> row (tid>>3)+l*64, physchunk tid&7
  // logical chunk = (tid&7) ^ ((tid>>3)&7)  [row&7 == (tid>>3)&7]
  const int clog = ((tid & 7) ^ ((tid >> 3) & 7)) * 8;   // element offset
  const _Float16* srcA = A + (size_t)(gm0 + (tid >> 3)) * K + clog;
  const _Float16* srcB = B + (size_t)(gn0 + (tid >> 3)) * K + clog;
  char* const dst0 = lds + tid * 16;

  auto SH = [&](int tile, int h) {   // stage half-tile h of K-tile `tile`
    const _Float16* s = (h < 2 ? srcA : srcB) + (size_t)((h & 1) * 128) * K
                        + tile * 64;
    char* d = dst0 + (tile & 1) * 65536 + h * 16384;
    gload_lds16(s, d);
    gload_lds16(s + (size_t)64 * K, d + 8192);
  };

  // ---- fragment read offsets (swizzled): row stride 128B, 16 rows = 2048B
  const int axor = fr & 7;
  const int pc0 = (fq ^ axor) * 16;         // kk=0 phys chunk byte
  const int pc1 = ((4 + fq) ^ axor) * 16;   // kk=1
  const int arb = (wm + fr) * 128;
  const int brb = 32768 + (wn + fr) * 128;

  f32x4 acc[8][4] = {};
  f16x8 af[4][2], b0[2][2], b1[2][2];

  // ---- prologue: tile 0 fully + h0 of tile 1
  SH(0, 0); SH(0, 1); SH(0, 2); SH(0, 3);
  if (nkt > 1) {
    SH(1, 0);
    asm volatile("s_waitcnt vmcnt(2)" ::: "memory");
  } else {
    asm volatile("s_waitcnt vmcnt(0)" ::: "memory");
  }
  __builtin_amdgcn_s_barrier();
  __builtin_amdgcn_sched_barrier(0);

#define PHASE_MID                                          \
  __builtin_amdgcn_s_barrier();                            \
  asm volatile("s_waitcnt lgkmcnt(0)" ::: "memory");       \
  __builtin_amdgcn_sched_barrier(0);                       \
  __builtin_amdgcn_s_setprio(1);
#define PHASE_END                                          \
  __builtin_amdgcn_s_setprio(0);                           \
  __builtin_amdgcn_sched_barrier(0);                       \
  __builtin_amdgcn_s_barrier();

  for (int t = 0; t < nkt; ++t) {
    const char* buf = lds + (t & 1) * 65536;
    const bool st1 = (t + 1) < nkt;

    // ---- P0: read af(mh0) 8 + b0 4; stage h1(t+1); MFMA m0-3 x n0-1
    #pragma unroll
    for (int mi = 0; mi < 4; ++mi) {
      af[mi][0] = *(const f16x8*)(buf + arb + mi * 2048 + pc0);
      af[mi][1] = *(const f16x8*)(buf + arb + mi * 2048 + pc1);
    }
    #pragma unroll
    for (int ni = 0; ni < 2; ++ni) {
      b0[ni][0] = *(const f16x8*)(buf + brb + ni * 2048 + pc0);
      b0[ni][1] = *(const f16x8*)(buf + brb + ni * 2048 + pc1);
    }
    if (st1) SH(t + 1, 1);
    PHASE_MID
    #pragma unroll
    for (int mi = 0; mi < 4; ++mi)
      #pragma unroll
      for (int ni = 0; ni < 2; ++ni)
        #pragma unroll
        for (int kk = 0; kk < 2; ++kk)
          acc[mi][ni] = MFMA16(af[mi][kk], b0[ni][kk], acc[mi][ni]);
    PHASE_END

    // ---- P1: read b1 4; stage h2(t+1); MFMA m0-3 x n2-3
    #pragma unroll
    for (int ni = 0; ni < 2; ++ni) {
      b1[ni][0] = *(const f16x8*)(buf + brb + (ni + 2) * 2048 + pc0);
      b1[ni][1] = *(const f16x8*)(buf + brb + (ni + 2) * 2048 + pc1);
    }
    if (st1) SH(t + 1, 2);
    PHASE_MID
    #pragma unroll
    for (int mi = 0; mi < 4; ++mi)
      #pragma unroll
      for (int ni = 0; ni < 2; ++ni)
        #pragma unroll
        for (int kk = 0; kk < 2; ++kk)
          acc[mi][ni + 2] = MFMA16(af[mi][kk], b1[ni][kk], acc[mi][ni + 2]);
    PHASE_END

    // ---- P2: read af(mh1) 8; stage h3(t+1); MFMA m4-7 x n0-1
    #pragma unroll
    for (int mi = 0; mi < 4; ++mi) {
      af[mi][0] = *(const f16x8*)(buf + arb + (mi + 4) * 2048 + pc0);
      af[mi][1] = *(const f16x8*)(buf + arb + (mi + 4) * 2048 + pc1);
    }
    if (st1) SH(t + 1, 3);
    PHASE_MID
    #pragma unroll
    for (int mi = 0; mi < 4; ++mi)
      #pragma unroll
      for (int ni = 0; ni < 2; ++ni)
        #pragma unroll
        for (int kk = 0; kk < 2; ++kk)
          acc[mi + 4][ni] = MFMA16(af[mi][kk], b0[ni][kk], acc[mi + 4][ni]);
    PHASE_END

    // ---- P3: stage h0(t+2); MFMA m4-7 x n2-3; boundary vmcnt(2)
    const bool st2 = (t + 2) < nkt;
    if (st2) SH(t + 2, 0);
    __builtin_amdgcn_s_barrier();
    __builtin_amdgcn_s_setprio(1);
    #pragma unroll
    for (int mi = 0; mi < 4; ++mi)
      #pragma unroll
      for (int ni = 0; ni < 2; ++ni)
        #pragma unroll
        for (int kk = 0; kk < 2; ++kk)
          acc[mi + 4][ni + 2] = MFMA16(af[mi][kk], b1[ni][kk], acc[mi + 4][ni + 2]);
    __builtin_amdgcn_s_setprio(0);
    __builtin_amdgcn_sched_barrier(0);
    if (st2) asm volatile("s_waitcnt vmcnt(2)" ::: "memory");
    else     asm volatile("s_waitcnt vmcnt(0)" ::: "memory");
    __builtin_amdgcn_s_barrier();
  }
#undef PHASE_MID
#undef PHASE_END

  // ---- epilogue: C/D layout col=fr, row=fq*4+r
  const int erow = gm0 + wm + fq * 4;
  const int ecol = gn0 + wn + fr;
  #pragma unroll
  for (int m = 0; m < 8; ++m)
    #pragma unroll
    for (int n = 0; n < 4; ++n) {
      size_t base = (size_t)(erow + m * 16) * N + (ecol + n * 16);
      #pragma unroll
      for (int r = 0; r < 4; ++r) {
        float v = acc[m][n][r];
        if constexpr (MODE == 0)
          ((float*)Cv + (size_t)bz * sCz)[base + (size_t)r * N] = v * scale;
        else if constexpr (MODE == 1)
          ((_Float16*)Cv + (size_t)bz * sCz)[base + (size_t)r * N] = (_Float16)v;
        else
          ((_Float16*)Cv + (size_t)bz * sCz)[base + (size_t)r * N] =
              (_Float16)(v * scale);
      }
    }
}

// ---------------------------------------------------------------------------
// gemm256 (round-6 proven): 256x128 tile, BK=32, 4-deep pipeline. MODE 0: f32.
template <int MODE>
__global__ __launch_bounds__(512, 2) void gemm256(
    const _Float16* __restrict__ At, size_t sA,
    const _Float16* __restrict__ Bt, size_t sB,
    void* __restrict__ C0v, size_t sCz,
    int N, int K, float scale)
{
  extern __shared__ char lds[];
  constexpr int BB = 128 * 64;
  char* ldsAb = lds;
  char* ldsBb = lds + 65536;

  int bx, by, bz;
  swz_block(bx, by, bz);
  const _Float16* A = At + (size_t)bz * sA;
  const _Float16* B = Bt + (size_t)bz * sB;

  const int gm0 = by * 256;
  const int gn0 = bx * 128;
  const int tid = threadIdx.x;
  const int lane = tid & 63, wave = tid >> 6;
  const int wm = (wave >> 1) * 64;
  const int wn = (wave & 1) * 64;
  const int fr = lane & 15, fq = lane >> 4;

  const int nkt = K >> 5;

  const int cbs = (((tid & 3) ^ ((tid >> 3) & 3)) << 4);
  const size_t aOff = (size_t)(gm0 + (tid >> 2)) * K + (cbs >> 1);
  const size_t bOff = (size_t)(gn0 + (tid >> 2)) * K + (cbs >> 1);
  const int cbr  = (fq * 16) ^ (((fr >> 1) & 3) << 4);
  const int arow = (wm + fr) * 64 + cbr;
  const int brow = (wn + fr) * 64 + cbr;

  f32x4 acc[4][4] = {};

  for (int tp = 0; tp < 3; ++tp) {
    const _Float16* gA = A + aOff + tp * 32;
    const _Float16* gB = B + bOff + tp * 32;
    char* dA = ldsAb + tp * 16384 + tid * 16;
    char* dB = ldsBb + tp * BB + tid * 16;
    gload_lds16(gA, dA);
    gload_lds16(gA + (size_t)128 * K, dA + 8192);
    gload_lds16(gB, dB);
  }
  asm volatile("s_waitcnt vmcnt(6)" ::: "memory");
  __builtin_amdgcn_s_barrier();
  __builtin_amdgcn_sched_barrier(0);

  for (int t = 0; t < nkt; ++t) {
    const char* pA = ldsAb + (t & 3) * 16384;
    const char* pB = ldsBb + (t & 3) * BB;
    const int tp = t + 3;
    const bool st = tp < nkt;
    const _Float16* gA = A + aOff + (st ? tp : 0) * 32;
    const _Float16* gB = B + bOff + (st ? tp : 0) * 32;
    char* dA = ldsAb + (tp & 3) * 16384 + tid * 16;
    char* dB = ldsBb + (tp & 3) * BB + tid * 16;

    if (st) { gload_lds16(gA, dA); gload_lds16(gB, dB); }
    f16x8 bfr[4], af[2];
    #pragma unroll
    for (int n = 0; n < 4; ++n) bfr[n] = *(const f16x8*)(pB + brow + n * 1024);
    #pragma unroll
    for (int m = 0; m < 2; ++m) af[m] = *(const f16x8*)(pA + arow + m * 1024);
    __builtin_amdgcn_s_setprio(1);
    #pragma unroll
    for (int m = 0; m < 2; ++m)
      #pragma unroll
      for (int n = 0; n < 4; ++n) acc[m][n] = MFMA16(af[m], bfr[n], acc[m][n]);
    __builtin_amdgcn_s_setprio(0);
    __builtin_amdgcn_s_barrier();
    __builtin_amdgcn_sched_barrier(0);

    if (st) gload_lds16(gA + (size_t)128 * K, dA + 8192);
    #pragma unroll
    for (int m = 0; m < 2; ++m) af[m] = *(const f16x8*)(pA + arow + (m + 2) * 1024);
    __builtin_amdgcn_s_setprio(1);
    #pragma unroll
    for (int m = 0; m < 2; ++m)
      #pragma unroll
      for (int n = 0; n < 4; ++n) acc[m + 2][n] = MFMA16(af[m], bfr[n], acc[m + 2][n]);
    __builtin_amdgcn_s_setprio(0);
    asm volatile("s_waitcnt vmcnt(6)" ::: "memory");
    __builtin_amdgcn_s_barrier();
    __builtin_amdgcn_sched_barrier(0);
  }

  const int erow = gm0 + wm + fq * 4;
  const int ecol = gn0 + wn + fr;
  float* C = (float*)C0v + (size_t)bz * sCz;
  #pragma unroll
  for (int m = 0; m < 4; ++m)
    #pragma unroll
    for (int n = 0; n < 4; ++n) {
      size_t base = (size_t)(erow + m * 16) * N + (ecol + n * 16);
      #pragma unroll
      for (int r = 0; r < 4; ++r)
        C[base + (size_t)r * N] = acc[m][n][r] * scale;
    }
}

// ---------------------------------------------------------------------------
// Wave-per-row softmax: scores [8192 rows][2048] f16 -> P f16. 4 rows/block.
__global__ __launch_bounds__(256) void softmax_rows(
    const _Float16* __restrict__ S, _Float16* __restrict__ P)
{
  const int w = threadIdx.x >> 6, lane = threadIdx.x & 63;
  const size_t row = (size_t)blockIdx.x * 4 + w;
  const _Float16* sr = S + row * 2048;

  f16x8 v[4];
  #pragma unroll
  for (int c = 0; c < 4; ++c)
    v[c] = *(const f16x8*)(sr + c * 512 + lane * 8);

  float m = -1e30f;
  #pragma unroll
  for (int c = 0; c < 4; ++c)
    #pragma unroll
    for (int j = 0; j < 8; ++j) m = fmaxf(m, (float)v[c][j]);
  #pragma unroll
  for (int o = 32; o >= 1; o >>= 1) m = fmaxf(m, __shfl_xor(m, o));

  float e[4][8];
  float s = 0.f;
  #pragma unroll
  for (int c = 0; c < 4; ++c)
    #pragma unroll
    for (int j = 0; j < 8; ++j) {
      e[c][j] = __expf((float)v[c][j] - m);
      s += e[c][j];
    }
  #pragma unroll
  for (int o = 32; o >= 1; o >>= 1) s += __shfl_xor(s, o);

  const float inv = 1.0f / s;
  _Float16* pr = P + row * 2048;
  #pragma unroll
  for (int c = 0; c < 4; ++c) {
    f16x8 p;
    #pragma unroll
    for (int j = 0; j < 8; ++j) p[j] = (_Float16)(e[c][j] * inv);
    *(f16x8*)(pr + c * 512 + lane * 8) = p;
  }
}

// ---------------------------------------------------------------------------
extern "C" void kernel_launch(void* const* d_in, const int* in_sizes, int n_in,
                              void* d_out, int out_size, void* d_ws, size_t ws_size,
                              hipStream_t stream)
{
  const float* Xk = (const float*)d_in[0];
  const float* Xv = (const float*)d_in[1];
  const float* Xq = (const float*)d_in[2];
  const float* WK = (const float*)d_in[3];
  const float* WV = (const float*)d_in[4];
  const float* WQ = (const float*)d_in[5];
  float* out = (float*)d_out;
  char* ws = (char*)d_ws;

  _Float16* XF   = (_Float16*)(ws);               // 0..48 MiB
  _Float16* WT   = (_Float16*)(ws + 48 * MiB);    // 48..54
  _Float16* PROJ = (_Float16*)(ws + 54 * MiB);    // 54..102 (K,V,Q)
  _Float16* VT   = (_Float16*)(ws + 102 * MiB);   // 102..118
  _Float16* SC   = (_Float16*)(ws + 118 * MiB);   // 118..150 (f16 scores)
  _Float16* P    = (_Float16*)(ws);               // alias XF (dead post-proj)

  _Float16* Kp = PROJ;
  _Float16* Vp = PROJ + MK;
  _Float16* Qp = PROJ + 2 * MK;

  auto* fP  = gemm8p<1>;
  auto* fSC = gemm8p<2>;
  auto* fPV = gemm256<0>;
  (void)hipFuncSetAttribute((const void*)fP,  hipFuncAttributeMaxDynamicSharedMemorySize, 131072);
  (void)hipFuncSetAttribute((const void*)fSC, hipFuncAttributeMaxDynamicSharedMemorySize, 131072);
  (void)hipFuncSetAttribute((const void*)fPV, hipFuncAttributeMaxDynamicSharedMemorySize, 98304);

  // 1) X -> f16 (k,v,q)
  convert_x<<<dim3(8192, 1, 3), 256, 0, stream>>>(Xk, Xv, Xq, XF);
  // 2) W -> W^T f16 (K,V,Q)
  transpose_conv_w<<<dim3(32, 32, 3), 256, 0, stream>>>(WK, WV, WQ, WT);
  // 3) projections: PROJ[z] = XF[z] @ WT[z]^T  (M=8192,N=1024,K=1024)
  gemm8p<1><<<dim3(4, 32, 3), 512, 131072, stream>>>(
      XF, MK, WT, WSZ, PROJ, MK, 1024, 1024, 1.0f);
  // 4) V^T per batch
  transpose_v<<<dim3(32, 64, 4), 256, 0, stream>>>(Vp, VT);
  // 5) scores[b] = Q[b]@K[b]^T / sqrt(2048) -> f16  (M=2048,N=2048,K=1024)
  gemm8p<2><<<dim3(8, 8, 4), 512, 131072, stream>>>(
      Qp, (size_t)2048 * 1024, Kp, (size_t)2048 * 1024,
      SC, (size_t)2048 * 2048, 2048, 1024, 0.022097086912079608f);
  // 6) softmax (wave-per-row) -> P f16
  softmax_rows<<<dim3(2048), 256, 0, stream>>>(SC, P);
  // 7) out[b] = P[b] @ VT[b]^T  (M=2048,N=1024,K=2048)
  gemm256<0><<<dim3(8, 8, 4), 512, 98304, stream>>>(
      P, (size_t)2048 * 2048, VT, (size_t)1024 * 2048,
      out, (size_t)2048 * 1024, 1024, 2048, 1.0f);
}

// Round 8
// 197.414 us; speedup vs baseline: 1.9276x; 1.0255x over previous
//
#include <hip/hip_runtime.h>
#include <hip/hip_bf16.h>

// ---------------------------------------------------------------------------
// AttentionHead B=4,S=2048,D=1024 — all-f16 pipeline, round 8.
// gemm8p : 256x256 BK=64 4-phase (r7, proven) — scores (grid 256 = 1 round).
// gemm8pN: 256x128 BK=64 2-phase (new)      — proj (768 = 3 rounds, fill 1.0)
//                                              and PV (256 = 1 round).
// R7 lesson: in-round rate ~947 TF is schedule-invariant; grid FILL was the
// proj loss (384 blocks = 1.5 rounds -> MfmaUtil 38%*0.75=27.5%).
// ws (MiB): XF@0(48) WT@48(6) PROJ@54(48) VT@102(16) SC@118(32,f16)
//           P@0(32,f16, alias XF). high-water 150 MiB.
// ---------------------------------------------------------------------------

typedef __attribute__((ext_vector_type(4))) float    f32x4;
typedef __attribute__((ext_vector_type(8))) _Float16 f16x8;
typedef __attribute__((ext_vector_type(4))) _Float16 f16x4;

constexpr size_t MiB = 1u << 20;
constexpr size_t MK  = (size_t)8192 * 1024;
constexpr size_t WSZ = (size_t)1024 * 1024;

__device__ __forceinline__ void gload_lds16(const void* g, void* l) {
  __builtin_amdgcn_global_load_lds(
      (const __attribute__((address_space(1))) unsigned int*)g,
      (__attribute__((address_space(3))) unsigned int*)l, 16, 0, 0);
}

#define MFMA16(a, b, c) __builtin_amdgcn_mfma_f32_16x16x32_f16(a, b, c, 0, 0, 0)

// XCD-chunked bijective block swizzle (requires total blocks % 8 == 0).
__device__ __forceinline__ void swz_block(int& bx, int& by, int& bz) {
  unsigned gx = gridDim.x, gy = gridDim.y;
  unsigned flat = blockIdx.x + gx * (blockIdx.y + gy * blockIdx.z);
  unsigned total = gx * gy * gridDim.z;
  unsigned cpx = total >> 3;
  unsigned s = (flat & 7) * cpx + (flat >> 3);
  bx = s % gx; s /= gx; by = s % gy; bz = s / gy;
}

// ---------------------------------------------------------------------------
__global__ __launch_bounds__(256) void convert_x(
    const float* __restrict__ x0, const float* __restrict__ x1,
    const float* __restrict__ x2, _Float16* __restrict__ XF)
{
  const int z = blockIdx.z;
  const float* x = z == 0 ? x0 : (z == 1 ? x1 : x2);
  size_t i = ((size_t)blockIdx.x * 256 + threadIdx.x) * 4;
  float4 v = *(const float4*)(x + i);
  f16x4 h = {(_Float16)v.x, (_Float16)v.y, (_Float16)v.z, (_Float16)v.w};
  *(f16x4*)(XF + (size_t)z * MK + i) = h;
}

// ---------------------------------------------------------------------------
__global__ __launch_bounds__(256) void transpose_conv_w(
    const float* __restrict__ w0, const float* __restrict__ w1,
    const float* __restrict__ w2, _Float16* __restrict__ WT)
{
  const int z = blockIdx.z;
  const float* W = z == 0 ? w0 : (z == 1 ? w1 : w2);
  _Float16* o = WT + (size_t)z * WSZ;
  __shared__ float tile[32][33];
  const int bx = blockIdx.x * 32;
  const int by = blockIdx.y * 32;
  const int tx = threadIdx.x & 31, ty = threadIdx.x >> 5;
  #pragma unroll
  for (int r = 0; r < 32; r += 8)
    tile[ty + r][tx] = W[(size_t)(by + ty + r) * 1024 + bx + tx];
  __syncthreads();
  #pragma unroll
  for (int r = 0; r < 32; r += 8)
    o[(size_t)(bx + ty + r) * 1024 + by + tx] = (_Float16)tile[tx][ty + r];
}

// ---------------------------------------------------------------------------
__global__ __launch_bounds__(256) void transpose_v(
    const _Float16* __restrict__ V, _Float16* __restrict__ Vt)
{
  const _Float16* v = V + (size_t)blockIdx.z * 2048 * 1024;
  _Float16* o = Vt + (size_t)blockIdx.z * 1024 * 2048;
  __shared__ _Float16 tile[32][33];
  const int bx = blockIdx.x * 32;   // e
  const int by = blockIdx.y * 32;   // s
  const int tx = threadIdx.x & 31, ty = threadIdx.x >> 5;
  #pragma unroll
  for (int r = 0; r < 32; r += 8)
    tile[ty + r][tx] = v[(size_t)(by + ty + r) * 1024 + bx + tx];
  __syncthreads();
  #pragma unroll
  for (int r = 0; r < 32; r += 8)
    o[(size_t)(bx + ty + r) * 2048 + by + tx] = tile[tx][ty + r];
}

// ---------------------------------------------------------------------------
// gemm8p (r7, unchanged): 256x256 BK=64, 4 phases/K-tile. For scores.
// MODE 0: f32*scale ; 1: f16 ; 2: f16*scale.
template <int MODE>
__global__ __launch_bounds__(512, 2) void gemm8p(
    const _Float16* __restrict__ At, size_t sA,
    const _Float16* __restrict__ Bt, size_t sB,
    void* __restrict__ Cv, size_t sCz,
    int N, int K, float scale)
{
  extern __shared__ char lds[];
  int bx, by, bz;
  swz_block(bx, by, bz);
  const _Float16* A = At + (size_t)bz * sA;
  const _Float16* B = Bt + (size_t)bz * sB;

  const int gm0 = by * 256, gn0 = bx * 256;
  const int tid = threadIdx.x;
  const int lane = tid & 63, wave = tid >> 6;
  const int wm = (wave >> 2) * 128;
  const int wn = (wave & 3) * 64;
  const int fr = lane & 15, fq = lane >> 4;
  const int nkt = K >> 6;

  const int clog = ((tid & 7) ^ ((tid >> 3) & 7)) * 8;
  const _Float16* srcA = A + (size_t)(gm0 + (tid >> 3)) * K + clog;
  const _Float16* srcB = B + (size_t)(gn0 + (tid >> 3)) * K + clog;
  char* const dst0 = lds + tid * 16;

  auto SH = [&](int tile, int h) {
    const _Float16* s = (h < 2 ? srcA : srcB) + (size_t)((h & 1) * 128) * K
                        + tile * 64;
    char* d = dst0 + (tile & 1) * 65536 + h * 16384;
    gload_lds16(s, d);
    gload_lds16(s + (size_t)64 * K, d + 8192);
  };

  const int axor = fr & 7;
  const int pc0 = (fq ^ axor) * 16;
  const int pc1 = ((4 + fq) ^ axor) * 16;
  const int arb = (wm + fr) * 128;
  const int brb = 32768 + (wn + fr) * 128;

  f32x4 acc[8][4] = {};
  f16x8 af[4][2], b0[2][2], b1[2][2];

  SH(0, 0); SH(0, 1); SH(0, 2); SH(0, 3);
  if (nkt > 1) {
    SH(1, 0);
    asm volatile("s_waitcnt vmcnt(2)" ::: "memory");
  } else {
    asm volatile("s_waitcnt vmcnt(0)" ::: "memory");
  }
  __builtin_amdgcn_s_barrier();
  __builtin_amdgcn_sched_barrier(0);

#define PHASE_MID                                          \
  __builtin_amdgcn_s_barrier();                            \
  asm volatile("s_waitcnt lgkmcnt(0)" ::: "memory");       \
  __builtin_amdgcn_sched_barrier(0);                       \
  __builtin_amdgcn_s_setprio(1);
#define PHASE_END                                          \
  __builtin_amdgcn_s_setprio(0);                           \
  __builtin_amdgcn_sched_barrier(0);                       \
  __builtin_amdgcn_s_barrier();

  for (int t = 0; t < nkt; ++t) {
    const char* buf = lds + (t & 1) * 65536;
    const bool st1 = (t + 1) < nkt;

    #pragma unroll
    for (int mi = 0; mi < 4; ++mi) {
      af[mi][0] = *(const f16x8*)(buf + arb + mi * 2048 + pc0);
      af[mi][1] = *(const f16x8*)(buf + arb + mi * 2048 + pc1);
    }
    #pragma unroll
    for (int ni = 0; ni < 2; ++ni) {
      b0[ni][0] = *(const f16x8*)(buf + brb + ni * 2048 + pc0);
      b0[ni][1] = *(const f16x8*)(buf + brb + ni * 2048 + pc1);
    }
    if (st1) SH(t + 1, 1);
    PHASE_MID
    #pragma unroll
    for (int mi = 0; mi < 4; ++mi)
      #pragma unroll
      for (int ni = 0; ni < 2; ++ni)
        #pragma unroll
        for (int kk = 0; kk < 2; ++kk)
          acc[mi][ni] = MFMA16(af[mi][kk], b0[ni][kk], acc[mi][ni]);
    PHASE_END

    #pragma unroll
    for (int ni = 0; ni < 2; ++ni) {
      b1[ni][0] = *(const f16x8*)(buf + brb + (ni + 2) * 2048 + pc0);
      b1[ni][1] = *(const f16x8*)(buf + brb + (ni + 2) * 2048 + pc1);
    }
    if (st1) SH(t + 1, 2);
    PHASE_MID
    #pragma unroll
    for (int mi = 0; mi < 4; ++mi)
      #pragma unroll
      for (int ni = 0; ni < 2; ++ni)
        #pragma unroll
        for (int kk = 0; kk < 2; ++kk)
          acc[mi][ni + 2] = MFMA16(af[mi][kk], b1[ni][kk], acc[mi][ni + 2]);
    PHASE_END

    #pragma unroll
    for (int mi = 0; mi < 4; ++mi) {
      af[mi][0] = *(const f16x8*)(buf + arb + (mi + 4) * 2048 + pc0);
      af[mi][1] = *(const f16x8*)(buf + arb + (mi + 4) * 2048 + pc1);
    }
    if (st1) SH(t + 1, 3);
    PHASE_MID
    #pragma unroll
    for (int mi = 0; mi < 4; ++mi)
      #pragma unroll
      for (int ni = 0; ni < 2; ++ni)
        #pragma unroll
        for (int kk = 0; kk < 2; ++kk)
          acc[mi + 4][ni] = MFMA16(af[mi][kk], b0[ni][kk], acc[mi + 4][ni]);
    PHASE_END

    const bool st2 = (t + 2) < nkt;
    if (st2) SH(t + 2, 0);
    __builtin_amdgcn_s_barrier();
    __builtin_amdgcn_s_setprio(1);
    #pragma unroll
    for (int mi = 0; mi < 4; ++mi)
      #pragma unroll
      for (int ni = 0; ni < 2; ++ni)
        #pragma unroll
        for (int kk = 0; kk < 2; ++kk)
          acc[mi + 4][ni + 2] = MFMA16(af[mi][kk], b1[ni][kk], acc[mi + 4][ni + 2]);
    __builtin_amdgcn_s_setprio(0);
    __builtin_amdgcn_sched_barrier(0);
    if (st2) asm volatile("s_waitcnt vmcnt(2)" ::: "memory");
    else     asm volatile("s_waitcnt vmcnt(0)" ::: "memory");
    __builtin_amdgcn_s_barrier();
  }
#undef PHASE_MID
#undef PHASE_END

  const int erow = gm0 + wm + fq * 4;
  const int ecol = gn0 + wn + fr;
  #pragma unroll
  for (int m = 0; m < 8; ++m)
    #pragma unroll
    for (int n = 0; n < 4; ++n) {
      size_t base = (size_t)(erow + m * 16) * N + (ecol + n * 16);
      #pragma unroll
      for (int r = 0; r < 4; ++r) {
        float v = acc[m][n][r];
        if constexpr (MODE == 0)
          ((float*)Cv + (size_t)bz * sCz)[base + (size_t)r * N] = v * scale;
        else if constexpr (MODE == 1)
          ((_Float16*)Cv + (size_t)bz * sCz)[base + (size_t)r * N] = (_Float16)v;
        else
          ((_Float16*)Cv + (size_t)bz * sCz)[base + (size_t)r * N] =
              (_Float16)(v * scale);
      }
    }
}

// ---------------------------------------------------------------------------
// gemm8pN (new): 256(M)x128(N) tile, BK=64, 512 thr = 8 waves (4M x 2N,
// per-wave 64x64). LDS 2 x 48KiB dbuf: A [256][64] @0, B [128][64] @32768.
// 2 phases/K-tile of 16 MFMA. Staging units of 16KiB (2 gloads):
// u0,u1 = A halves, u2 = B. P0 stages u1,u2(t+1); P1 stages u0(t+2);
// boundary vmcnt(2) steady / vmcnt(0) tail. Same swizzle as gemm8p.
// MODE 0: f32*scale ; 1: f16.
template <int MODE>
__global__ __launch_bounds__(512, 2) void gemm8pN(
    const _Float16* __restrict__ At, size_t sA,
    const _Float16* __restrict__ Bt, size_t sB,
    void* __restrict__ Cv, size_t sCz,
    int N, int K, float scale)
{
  extern __shared__ char lds[];
  int bx, by, bz;
  swz_block(bx, by, bz);
  const _Float16* A = At + (size_t)bz * sA;
  const _Float16* B = Bt + (size_t)bz * sB;

  const int gm0 = by * 256, gn0 = bx * 128;
  const int tid = threadIdx.x;
  const int lane = tid & 63, wave = tid >> 6;
  const int wm = (wave >> 1) * 64;    // 4 M groups of 64
  const int wn = (wave & 1) * 64;     // 2 N groups of 64
  const int fr = lane & 15, fq = lane >> 4;
  const int nkt = K >> 6;

  const int clog = ((tid & 7) ^ ((tid >> 3) & 7)) * 8;
  const _Float16* srcA = A + (size_t)(gm0 + (tid >> 3)) * K + clog;
  const _Float16* srcB = B + (size_t)(gn0 + (tid >> 3)) * K + clog;
  char* const dst0 = lds + tid * 16;

  // unit u: u0=A rows 0-127, u1=A rows 128-255, u2=B rows 0-127 (16KiB each)
  auto SHU = [&](int tile, int u) {
    const _Float16* s = (u < 2 ? srcA + (size_t)(u * 128) * K : srcB)
                        + tile * 64;
    char* d = dst0 + (tile & 1) * 49152 + u * 16384;
    gload_lds16(s, d);
    gload_lds16(s + (size_t)64 * K, d + 8192);
  };

  const int axor = fr & 7;
  const int pc0 = (fq ^ axor) * 16;
  const int pc1 = ((4 + fq) ^ axor) * 16;
  const int arb = (wm + fr) * 128;
  const int brb = 32768 + (wn + fr) * 128;

  f32x4 acc[4][4] = {};
  f16x8 af[4][2], b0[2][2], b1[2][2];

  // prologue: tile 0 fully + u0 of tile 1
  SHU(0, 0); SHU(0, 1); SHU(0, 2);
  if (nkt > 1) {
    SHU(1, 0);
    asm volatile("s_waitcnt vmcnt(2)" ::: "memory");
  } else {
    asm volatile("s_waitcnt vmcnt(0)" ::: "memory");
  }
  __builtin_amdgcn_s_barrier();
  __builtin_amdgcn_sched_barrier(0);

#define PHASE_MID                                          \
  __builtin_amdgcn_s_barrier();                            \
  asm volatile("s_waitcnt lgkmcnt(0)" ::: "memory");       \
  __builtin_amdgcn_sched_barrier(0);                       \
  __builtin_amdgcn_s_setprio(1);
#define PHASE_END                                          \
  __builtin_amdgcn_s_setprio(0);                           \
  __builtin_amdgcn_sched_barrier(0);                       \
  __builtin_amdgcn_s_barrier();

  for (int t = 0; t < nkt; ++t) {
    const char* buf = lds + (t & 1) * 49152;
    const bool st1 = (t + 1) < nkt;
    const bool st2 = (t + 2) < nkt;

    // ---- P0: read af(8) + b0(4); stage u1,u2(t+1); MFMA m0-3 x n0-1
    #pragma unroll
    for (int mi = 0; mi < 4; ++mi) {
      af[mi][0] = *(const f16x8*)(buf + arb + mi * 2048 + pc0);
      af[mi][1] = *(const f16x8*)(buf + arb + mi * 2048 + pc1);
    }
    #pragma unroll
    for (int ni = 0; ni < 2; ++ni) {
      b0[ni][0] = *(const f16x8*)(buf + brb + ni * 2048 + pc0);
      b0[ni][1] = *(const f16x8*)(buf + brb + ni * 2048 + pc1);
    }
    if (st1) { SHU(t + 1, 1); SHU(t + 1, 2); }
    PHASE_MID
    #pragma unroll
    for (int mi = 0; mi < 4; ++mi)
      #pragma unroll
      for (int ni = 0; ni < 2; ++ni)
        #pragma unroll
        for (int kk = 0; kk < 2; ++kk)
          acc[mi][ni] = MFMA16(af[mi][kk], b0[ni][kk], acc[mi][ni]);
    PHASE_END

    // ---- P1: read b1(4); stage u0(t+2); MFMA m0-3 x n2-3; boundary vmcnt
    #pragma unroll
    for (int ni = 0; ni < 2; ++ni) {
      b1[ni][0] = *(const f16x8*)(buf + brb + (ni + 2) * 2048 + pc0);
      b1[ni][1] = *(const f16x8*)(buf + brb + (ni + 2) * 2048 + pc1);
    }
    if (st2) SHU(t + 2, 0);
    __builtin_amdgcn_s_barrier();
    asm volatile("s_waitcnt lgkmcnt(0)" ::: "memory");
    __builtin_amdgcn_sched_barrier(0);
    __builtin_amdgcn_s_setprio(1);
    #pragma unroll
    for (int mi = 0; mi < 4; ++mi)
      #pragma unroll
      for (int ni = 0; ni < 2; ++ni)
        #pragma unroll
        for (int kk = 0; kk < 2; ++kk)
          acc[mi][ni + 2] = MFMA16(af[mi][kk], b1[ni][kk], acc[mi][ni + 2]);
    __builtin_amdgcn_s_setprio(0);
    __builtin_amdgcn_sched_barrier(0);
    if (st2)      asm volatile("s_waitcnt vmcnt(2)" ::: "memory");
    else          asm volatile("s_waitcnt vmcnt(0)" ::: "memory");
    __builtin_amdgcn_s_barrier();
  }
#undef PHASE_MID
#undef PHASE_END

  const int erow = gm0 + wm + fq * 4;
  const int ecol = gn0 + wn + fr;
  #pragma unroll
  for (int m = 0; m < 4; ++m)
    #pragma unroll
    for (int n = 0; n < 4; ++n) {
      size_t base = (size_t)(erow + m * 16) * N + (ecol + n * 16);
      #pragma unroll
      for (int r = 0; r < 4; ++r) {
        float v = acc[m][n][r];
        if constexpr (MODE == 0)
          ((float*)Cv + (size_t)bz * sCz)[base + (size_t)r * N] = v * scale;
        else
          ((_Float16*)Cv + (size_t)bz * sCz)[base + (size_t)r * N] = (_Float16)v;
      }
    }
}

// ---------------------------------------------------------------------------
// Wave-per-row softmax: scores [8192 rows][2048] f16 -> P f16. 4 rows/block.
__global__ __launch_bounds__(256) void softmax_rows(
    const _Float16* __restrict__ S, _Float16* __restrict__ P)
{
  const int w = threadIdx.x >> 6, lane = threadIdx.x & 63;
  const size_t row = (size_t)blockIdx.x * 4 + w;
  const _Float16* sr = S + row * 2048;

  f16x8 v[4];
  #pragma unroll
  for (int c = 0; c < 4; ++c)
    v[c] = *(const f16x8*)(sr + c * 512 + lane * 8);

  float m = -1e30f;
  #pragma unroll
  for (int c = 0; c < 4; ++c)
    #pragma unroll
    for (int j = 0; j < 8; ++j) m = fmaxf(m, (float)v[c][j]);
  #pragma unroll
  for (int o = 32; o >= 1; o >>= 1) m = fmaxf(m, __shfl_xor(m, o));

  float e[4][8];
  float s = 0.f;
  #pragma unroll
  for (int c = 0; c < 4; ++c)
    #pragma unroll
    for (int j = 0; j < 8; ++j) {
      e[c][j] = __expf((float)v[c][j] - m);
      s += e[c][j];
    }
  #pragma unroll
  for (int o = 32; o >= 1; o >>= 1) s += __shfl_xor(s, o);

  const float inv = 1.0f / s;
  _Float16* pr = P + row * 2048;
  #pragma unroll
  for (int c = 0; c < 4; ++c) {
    f16x8 p;
    #pragma unroll
    for (int j = 0; j < 8; ++j) p[j] = (_Float16)(e[c][j] * inv);
    *(f16x8*)(pr + c * 512 + lane * 8) = p;
  }
}

// ---------------------------------------------------------------------------
extern "C" void kernel_launch(void* const* d_in, const int* in_sizes, int n_in,
                              void* d_out, int out_size, void* d_ws, size_t ws_size,
                              hipStream_t stream)
{
  const float* Xk = (const float*)d_in[0];
  const float* Xv = (const float*)d_in[1];
  const float* Xq = (const float*)d_in[2];
  const float* WK = (const float*)d_in[3];
  const float* WV = (const float*)d_in[4];
  const float* WQ = (const float*)d_in[5];
  float* out = (float*)d_out;
  char* ws = (char*)d_ws;

  _Float16* XF   = (_Float16*)(ws);               // 0..48 MiB
  _Float16* WT   = (_Float16*)(ws + 48 * MiB);    // 48..54
  _Float16* PROJ = (_Float16*)(ws + 54 * MiB);    // 54..102 (K,V,Q)
  _Float16* VT   = (_Float16*)(ws + 102 * MiB);   // 102..118
  _Float16* SC   = (_Float16*)(ws + 118 * MiB);   // 118..150 (f16 scores)
  _Float16* P    = (_Float16*)(ws);               // alias XF (dead post-proj)

  _Float16* Kp = PROJ;
  _Float16* Vp = PROJ + MK;
  _Float16* Qp = PROJ + 2 * MK;

  auto* fP  = gemm8pN<1>;
  auto* fSC = gemm8p<2>;
  auto* fPV = gemm8pN<0>;
  (void)hipFuncSetAttribute((const void*)fP,  hipFuncAttributeMaxDynamicSharedMemorySize, 98304);
  (void)hipFuncSetAttribute((const void*)fSC, hipFuncAttributeMaxDynamicSharedMemorySize, 131072);
  (void)hipFuncSetAttribute((const void*)fPV, hipFuncAttributeMaxDynamicSharedMemorySize, 98304);

  // 1) X -> f16 (k,v,q)
  convert_x<<<dim3(8192, 1, 3), 256, 0, stream>>>(Xk, Xv, Xq, XF);
  // 2) W -> W^T f16 (K,V,Q)
  transpose_conv_w<<<dim3(32, 32, 3), 256, 0, stream>>>(WK, WV, WQ, WT);
  // 3) projections: PROJ[z] = XF[z] @ WT[z]^T  (M=8192,N=1024,K=1024)
  //    grid 8x32x3 = 768 blocks = 3.0 rounds (fill 1.0)
  gemm8pN<1><<<dim3(8, 32, 3), 512, 98304, stream>>>(
      XF, MK, WT, WSZ, PROJ, MK, 1024, 1024, 1.0f);
  // 4) V^T per batch
  transpose_v<<<dim3(32, 64, 4), 256, 0, stream>>>(Vp, VT);
  // 5) scores[b] = Q[b]@K[b]^T / sqrt(2048) -> f16  (grid 256 = 1 round)
  gemm8p<2><<<dim3(8, 8, 4), 512, 131072, stream>>>(
      Qp, (size_t)2048 * 1024, Kp, (size_t)2048 * 1024,
      SC, (size_t)2048 * 2048, 2048, 1024, 0.022097086912079608f);
  // 6) softmax (wave-per-row) -> P f16
  softmax_rows<<<dim3(2048), 256, 0, stream>>>(SC, P);
  // 7) out[b] = P[b] @ VT[b]^T  (M=2048,N=1024,K=2048; grid 256 = 1 round)
  gemm8pN<0><<<dim3(8, 8, 4), 512, 98304, stream>>>(
      P, (size_t)2048 * 2048, VT, (size_t)1024 * 2048,
      out, (size_t)2048 * 1024, 1024, 2048, 1.0f);
}